// Round 1
// 397.586 us; speedup vs baseline: 1.0041x; 1.0041x over previous
//
#include <hip/hip_runtime.h>
#include <hip/hip_bf16.h>

#define N_USERS 100000
#define N_ITEMS 50000
#define N_NODES 150000
#define DIM 64
#define N_EDGES 4000000
#define BATCH 4096

#define NBKT 512
#define BW 294           // nodes per bucket; 512*294 = 150528 >= 150000
#define STRIDE 9216      // tmp records per bucket (mean 7840, sigma ~88 -> +15.6 sigma)
#define PA_EDGES 4096    // edges per partition block
#define PA_ITER 16       // edges per thread (register-cached)
#define SCAP 384         // sampled-edge staging slots per partition block (mean ~217)
#define SLIST_CAP 262144

// ---------------- bf16 helpers ----------------
__device__ __forceinline__ float blo(unsigned int u) { return __uint_as_float(u << 16); }
__device__ __forceinline__ float bhi(unsigned int u) { return __uint_as_float(u & 0xffff0000u); }
__device__ __forceinline__ unsigned int f2b(float f) {  // RTNE
    unsigned int x = __float_as_uint(f);
    return (x + 0x7fffu + ((x >> 16) & 1u)) >> 16;
}
__device__ __forceinline__ unsigned int pack2(float a, float b) {
    return f2b(a) | (f2b(b) << 16);
}

typedef float v2f __attribute__((ext_vector_type(2)));

// fp32 tables -> bf16 concat table, fused with sampled-node marking + counter init
__global__ void k_markcvt(const float* __restrict__ uemb, const float* __restrict__ iemb,
                          ushort* __restrict__ out, const int* __restrict__ users,
                          const int* __restrict__ items, int* __restrict__ map,
                          int* __restrict__ sdeg, int* __restrict__ sfill,
                          int* __restrict__ gcur, int* __restrict__ scnt) {
    int tid = blockIdx.x * blockDim.x + threadIdx.x;
    if (tid < 2 * BATCH) {
        sdeg[tid] = 0;
        sfill[tid] = 0;
        if (tid < NBKT) gcur[tid] = 0;
        if (tid == 0) scnt[0] = 0;
        if (tid < BATCH) map[users[tid]] = tid;          // dup race: any winner is canonical
        else map[items[tid - BATCH] + N_USERS] = tid;    // tid = BATCH + b
    }
    int i = tid * 4;
    if (i >= N_NODES * DIM) return;
    const float* srcp = (i < N_USERS * DIM) ? (uemb + i) : (iemb + (i - N_USERS * DIM));
    float4 v;
    v.x = __builtin_nontemporal_load(srcp + 0);
    v.y = __builtin_nontemporal_load(srcp + 1);
    v.z = __builtin_nontemporal_load(srcp + 2);
    v.w = __builtin_nontemporal_load(srcp + 3);
    *(uint2*)(out + i) = make_uint2(pack2(v.x, v.y), pack2(v.z, v.w));
}

// ---------------- two-pass register-cached partition + sampled-edge filter ----------------
// pass 1: edges -> registers, LDS histogram; reserve per-bin global runs; pass 2: scatter
// from registers into reserved runs (per-block ~128B runs per bin -> L2 write-combines).
__global__ void __launch_bounds__(256, 4) k_partition(
        const int* __restrict__ src, const int* __restrict__ dst,
        const float* __restrict__ vals, const int* __restrict__ map,
        int* __restrict__ gcur, int2* __restrict__ tmp,
        int* __restrict__ sdeg, int* __restrict__ scnt,
        unsigned long long* __restrict__ slist) {
    __shared__ int cnt[NBKT];     // pass-1 histogram, then reused as pass-2 cursor
    __shared__ int base_s[NBKT];  // reserved global run base per bin
    __shared__ unsigned long long sbuf[SCAP];  // sampled-edge staging
    __shared__ int scnt_s, sbase_s;
    int t = threadIdx.x;
    for (int i = t; i < NBKT; i += 256) cnt[i] = 0;
    if (t == 0) scnt_s = 0;
    __syncthreads();
    size_t base = (size_t)blockIdx.x * PA_EDGES;
    int myb[PA_ITER];
    int mykey[PA_ITER];
    int myval[PA_ITER];
#pragma unroll
    for (int it = 0; it < PA_ITER; it++) {
        size_t i = base + (size_t)it * 256 + t;
        myb[it] = -1;
        if (i < N_EDGES) {
            int d = __builtin_nontemporal_load(dst + i);
            int s = __builtin_nontemporal_load(src + i);
            float v = __builtin_nontemporal_load(vals + i);
            int b = d / BW;
            int local = d - b * BW;
            myb[it] = b;
            mykey[it] = (s << 9) | local;
            myval[it] = __float_as_int(v);
            atomicAdd(&cnt[b], 1);
            int ms = map[d];
            if (ms >= 0) {  // edge feeds a sampled node's layer-3 row
                atomicAdd(&sdeg[ms], 1);
                unsigned long long pk = ((unsigned long long)(unsigned int)__float_as_int(v) << 32) |
                                        ((unsigned int)ms << 18) | (unsigned int)s;
                int sl = atomicAdd(&scnt_s, 1);
                if (sl < SCAP) sbuf[sl] = pk;
                else slist[atomicAdd(scnt, 1)] = pk;  // very rare
            }
        }
    }
    __syncthreads();
    // reserve global runs (one atomic per non-empty bin)
    for (int i = t; i < NBKT; i += 256) {
        int c = cnt[i];
        base_s[i] = (c > 0) ? atomicAdd(&gcur[i], c) : 0;
    }
    if (t == 0) {
        int c = min(scnt_s, SCAP);
        sbase_s = (c > 0) ? atomicAdd(scnt, c) : 0;
    }
    __syncthreads();
    for (int i = t; i < NBKT; i += 256) cnt[i] = 0;  // reuse as cursor
    __syncthreads();
    // drain sampled staging (coalesced)
    int stot = min(scnt_s, SCAP);
    for (int i = t; i < stot; i += 256) slist[sbase_s + i] = sbuf[i];
    // pass 2: scatter records from registers into reserved runs
#pragma unroll
    for (int it = 0; it < PA_ITER; it++) {
        int b = myb[it];
        if (b >= 0) {
            int pos = base_s[b] + atomicAdd(&cnt[b], 1);
            tmp[(size_t)b * STRIDE + pos] = make_int2(mykey[it], myval[it]);
        }
    }
}

// fused scans: block 0 = bucket scan (gcur -> bucket_ptr), block 1 = sampled scan (sdeg -> srow)
__global__ void k_scan2(const int* __restrict__ gcur, int* __restrict__ bucket_ptr,
                        const int* __restrict__ sdeg, int* __restrict__ srow) {
    __shared__ int ws[16];
    int t = threadIdx.x;  // 1024
    if (blockIdx.x == 0) {
        if (t >= 64) return;
        int lane = t;
        int carry = 0;
        for (int c = 0; c < NBKT / 64; c++) {
            int i = c * 64 + lane;
            int x = gcur[i];
            int incl = x;
            for (int off = 1; off < 64; off <<= 1) {
                int y = __shfl_up(incl, off);
                if (lane >= off) incl += y;
            }
            bucket_ptr[i] = carry + incl - x;
            carry += __shfl(incl, 63);
        }
        if (lane == 0) bucket_ptr[NBKT] = N_EDGES;
        return;
    }
    int v[8], p = 0;
#pragma unroll
    for (int j = 0; j < 8; j++) { v[j] = sdeg[t * 8 + j]; p += v[j]; }
    int lane = t & 63, w = t >> 6;
    int incl = p;
    for (int o = 1; o < 64; o <<= 1) {
        int y = __shfl_up(incl, o);
        if (lane >= o) incl += y;
    }
    if (lane == 63) ws[w] = incl;
    __syncthreads();
    int woff = 0;
    for (int j = 0; j < w; j++) woff += ws[j];
    int run = woff + incl - p;
#pragma unroll
    for (int j = 0; j < 8; j++) { srow[t * 8 + j] = run; run += v[j]; }
    if (t == 1023) srow[8192] = run;
}

// scatter sampled edges into slot-grouped sfin
__global__ void k_sscatter(const unsigned long long* __restrict__ slist,
                           const int* __restrict__ scnt, const int* __restrict__ srow,
                           int* __restrict__ sfill, int2* __restrict__ sfin) {
    int i = blockIdx.x * blockDim.x + threadIdx.x;
    if (i >= scnt[0]) return;
    unsigned long long pk = slist[i];
    int s = (int)(pk & 0x3FFFFu);
    int slot = (int)((pk >> 18) & 8191u);
    int vbits = (int)(pk >> 32);
    int pos = srow[slot] + atomicAdd(&sfill[slot], 1);
    sfin[pos] = make_int2(s, vbits);
}

// ---------------- pass B: sort within bucket (LDS hist + scan), emit dense CSR ----------------
// plain tmp loads: each block re-reads its ~74 KB bucket twice; it fits L2, NT would evict
__global__ void k_bsort(const int2* __restrict__ tmp, const int* __restrict__ gcur,
                        const int* __restrict__ bucket_ptr, int* __restrict__ row_ptr,
                        int2* __restrict__ fin) {
    __shared__ int cnt[BW + 64];
    __shared__ int off[BW + 64];
    int b = blockIdx.x, t = threadIdx.x;  // 512 threads
    int node0 = b * BW;
    int nodes = min(BW, N_NODES - node0);  // may be negative for trailing empty buckets
    int gbase = bucket_ptr[b];
    int count = gcur[b];
    const int2* tb = tmp + (size_t)b * STRIDE;
    for (int i = t; i < BW + 64; i += 512) cnt[i] = 0;
    __syncthreads();
    for (int e = t; e < count; e += 512) atomicAdd(&cnt[tb[e].x & 511], 1);
    __syncthreads();
    if (t < 64) {
        int lane = t;
        int carry = 0;
        for (int c = 0; c < 5; c++) {
            int i = c * 64 + lane;
            int x = (i < nodes) ? cnt[i] : 0;
            int incl = x;
            for (int o = 1; o < 64; o <<= 1) {
                int y = __shfl_up(incl, o);
                if (lane >= o) incl += y;
            }
            if (i <= nodes) off[i] = carry + incl - x;
            carry += __shfl(incl, 63);
        }
    }
    __syncthreads();
    for (int i = t; i <= nodes; i += 512)
        if (node0 + i <= N_NODES) row_ptr[node0 + i] = gbase + off[i];
    __syncthreads();
    for (int e = t; e < count; e += 512) {
        int2 r = tb[e];
        int local = r.x & 511;
        int pos = gbase + atomicAdd(&off[local], 1);
        fin[pos] = make_int2(r.x >> 9, r.y);  // plain store: L2 write-combines the region
    }
}

// ---------------- bf16 SpMM: one wave per dst node, 8 groups x 8 lanes ----------------
// v2: 32-bit SADDR offsets, v_pk_fma_f32 accumulation, 3-tier loop (4/2/1 gathers in flight).
// PLAIN fin loads (each 128B line consumed within one wave iteration) and PLAIN eout store;
// NT variants regressed (R7/R8).

// one edge record: gather 16B of the src row, packed-FMA into 4x float2 accumulators
#define EDGE_FMA(r, u)                                                        \
    {                                                                         \
        float vf = __int_as_float((r).y);                                     \
        v2f vv = {vf, vf};                                                    \
        v2f f0 = {blo((u).x), bhi((u).x)};                                    \
        v2f f1 = {blo((u).y), bhi((u).y)};                                    \
        v2f f2 = {blo((u).z), bhi((u).z)};                                    \
        v2f f3 = {blo((u).w), bhi((u).w)};                                    \
        acc0 = __builtin_elementwise_fma(vv, f0, acc0);                       \
        acc1 = __builtin_elementwise_fma(vv, f1, acc1);                       \
        acc2 = __builtin_elementwise_fma(vv, f2, acc2);                       \
        acc3 = __builtin_elementwise_fma(vv, f3, acc3);                       \
    }

// 32-bit byte offsets: table is 19.2 MB, record arrays <= 32 MB -> SADDR + voffset form
#define GATHER16(basec, r) (*(const uint4*)((basec) + ((((unsigned int)(r).x) << 7) | qoff)))
#define REC8(basec, i) (*(const int2*)((basec) + (((unsigned int)(i)) << 3)))

__global__ void k_spmm16(const ushort* __restrict__ ein, ushort* __restrict__ eout,
                         const int* __restrict__ row_ptr, const int2* __restrict__ fin) {
    int wave = (blockIdx.x * blockDim.x + threadIdx.x) >> 6;
    if (wave >= N_NODES) return;
    int lane = threadIdx.x & 63;
    int g = lane >> 3;  // edge group 0..7
    int q = lane & 7;   // 8 bf16 dims per lane
    unsigned int qoff = (unsigned int)q << 4;
    const char* einc = (const char*)ein;
    const char* finc = (const char*)fin;
    int start = row_ptr[wave], end = row_ptr[wave + 1];
    v2f acc0 = {0.f, 0.f}, acc1 = {0.f, 0.f}, acc2 = {0.f, 0.f}, acc3 = {0.f, 0.f};
    int e = start + g;
    // tier 1: 32 edges/iter, 4 gathers in flight (deg >= 33 nodes)
    for (; e + 24 < end; e += 32) {
        int2 ra = REC8(finc, e);
        int2 rb = REC8(finc, e + 8);
        int2 rc = REC8(finc, e + 16);
        int2 rd = REC8(finc, e + 24);
        uint4 ua = GATHER16(einc, ra);
        uint4 ub = GATHER16(einc, rb);
        uint4 uc = GATHER16(einc, rc);
        uint4 ud = GATHER16(einc, rd);
        EDGE_FMA(ra, ua);
        EDGE_FMA(rb, ub);
        EDGE_FMA(rc, uc);
        EDGE_FMA(rd, ud);
    }
    // tier 2: 16 edges/iter, 2 gathers in flight
    for (; e + 8 < end; e += 16) {
        int2 ra = REC8(finc, e);
        int2 rb = REC8(finc, e + 8);
        uint4 ua = GATHER16(einc, ra);
        uint4 ub = GATHER16(einc, rb);
        EDGE_FMA(ra, ua);
        EDGE_FMA(rb, ub);
    }
    // tier 3: at most one record left per lane (stride-8 groups invariant)
    if (e < end) {
        int2 ra = REC8(finc, e);
        uint4 ua = GATHER16(einc, ra);
        EDGE_FMA(ra, ua);
    }
#pragma unroll
    for (int off = 8; off < 64; off <<= 1) {
        acc0.x += __shfl_xor(acc0.x, off);
        acc0.y += __shfl_xor(acc0.y, off);
        acc1.x += __shfl_xor(acc1.x, off);
        acc1.y += __shfl_xor(acc1.y, off);
        acc2.x += __shfl_xor(acc2.x, off);
        acc2.y += __shfl_xor(acc2.y, off);
        acc3.x += __shfl_xor(acc3.x, off);
        acc3.y += __shfl_xor(acc3.y, off);
    }
    if (lane < 8) {
        uint4 p;
        p.x = pack2(acc0.x, acc0.y);
        p.y = pack2(acc1.x, acc1.y);
        p.z = pack2(acc2.x, acc2.y);
        p.w = pack2(acc3.x, acc3.y);
        *(uint4*)(eout + (size_t)wave * DIM + q * 8) = p;
    }
}

// layer-3 at sampled slots only -> l3 (overwrite; zero rows for empty slots)
__global__ void k_samp(const ushort* __restrict__ ein, const int* __restrict__ srow,
                       const int2* __restrict__ sfin, float* __restrict__ l3) {
    int slot = (blockIdx.x * blockDim.x + threadIdx.x) >> 6;
    if (slot >= 2 * BATCH) return;
    int lane = threadIdx.x & 63;
    int g = lane >> 3;
    int q = lane & 7;
    unsigned int qoff = (unsigned int)q << 4;
    const char* einc = (const char*)ein;
    const char* sfc = (const char*)sfin;
    int start = srow[slot], end = srow[slot + 1];
    v2f acc0 = {0.f, 0.f}, acc1 = {0.f, 0.f}, acc2 = {0.f, 0.f}, acc3 = {0.f, 0.f};
    int e = start + g;
    for (; e + 24 < end; e += 32) {
        int2 ra = REC8(sfc, e);
        int2 rb = REC8(sfc, e + 8);
        int2 rc = REC8(sfc, e + 16);
        int2 rd = REC8(sfc, e + 24);
        uint4 ua = GATHER16(einc, ra);
        uint4 ub = GATHER16(einc, rb);
        uint4 uc = GATHER16(einc, rc);
        uint4 ud = GATHER16(einc, rd);
        EDGE_FMA(ra, ua);
        EDGE_FMA(rb, ub);
        EDGE_FMA(rc, uc);
        EDGE_FMA(rd, ud);
    }
    for (; e + 8 < end; e += 16) {
        int2 ra = REC8(sfc, e);
        int2 rb = REC8(sfc, e + 8);
        uint4 ua = GATHER16(einc, ra);
        uint4 ub = GATHER16(einc, rb);
        EDGE_FMA(ra, ua);
        EDGE_FMA(rb, ub);
    }
    if (e < end) {
        int2 ra = REC8(sfc, e);
        uint4 ua = GATHER16(einc, ra);
        EDGE_FMA(ra, ua);
    }
#pragma unroll
    for (int off = 8; off < 64; off <<= 1) {
        acc0.x += __shfl_xor(acc0.x, off);
        acc0.y += __shfl_xor(acc0.y, off);
        acc1.x += __shfl_xor(acc1.x, off);
        acc1.y += __shfl_xor(acc1.y, off);
        acc2.x += __shfl_xor(acc2.x, off);
        acc2.y += __shfl_xor(acc2.y, off);
        acc3.x += __shfl_xor(acc3.x, off);
        acc3.y += __shfl_xor(acc3.y, off);
    }
    if (lane < 8) {
        float* row = l3 + (size_t)slot * DIM + q * 8;
        *(float4*)row = make_float4(acc0.x, acc0.y, acc1.x, acc1.y);
        *(float4*)(row + 4) = make_float4(acc2.x, acc2.y, acc3.x, acc3.y);
    }
}

// layer-0 + layer-1: acc = fp32 table row + bf16 ebf1 row (fused, overwrite)
__global__ void k_gacc0(const float* __restrict__ uemb, const float* __restrict__ iemb,
                        const ushort* __restrict__ emb, const int* __restrict__ users,
                        const int* __restrict__ items, float* __restrict__ accU,
                        float* __restrict__ accI) {
    int i = blockIdx.x * blockDim.x + threadIdx.x;
    if (i >= 2 * BATCH * DIM) return;
    int j = (i < BATCH * DIM) ? i : i - BATCH * DIM;
    int b = j >> 6, l = j & 63;
    if (i < BATCH * DIM) {
        int n = users[b];
        unsigned int u = emb[(size_t)n * DIM + l];
        accU[j] = uemb[(size_t)n * DIM + l] + __uint_as_float(u << 16);
    } else {
        int n = items[b];
        unsigned int u = emb[(size_t)(n + N_USERS) * DIM + l];
        accI[j] = iemb[(size_t)n * DIM + l] + __uint_as_float(u << 16);
    }
}

// layer-2: accumulate both sample sets from bf16 table
__global__ void k_gacc(const ushort* __restrict__ emb, const int* __restrict__ users,
                       const int* __restrict__ items, float* __restrict__ accU,
                       float* __restrict__ accI) {
    int i = blockIdx.x * blockDim.x + threadIdx.x;
    if (i >= 2 * BATCH * DIM) return;
    int j = (i < BATCH * DIM) ? i : i - BATCH * DIM;
    int b = j >> 6, l = j & 63;
    if (i < BATCH * DIM) {
        unsigned int u = emb[(size_t)users[b] * DIM + l];
        accU[j] += __uint_as_float(u << 16);
    } else {
        unsigned int u = emb[(size_t)(items[b] + N_USERS) * DIM + l];
        accI[j] += __uint_as_float(u << 16);
    }
}

// final dot: (acc + l3[canonical slot]) pairs
__global__ void k_dot(const float* __restrict__ accU, const float* __restrict__ accI,
                      const float* __restrict__ l3, const int* __restrict__ map,
                      const int* __restrict__ users, const int* __restrict__ items,
                      float* __restrict__ out) {
    int b = (blockIdx.x * blockDim.x + threadIdx.x) >> 6;
    if (b >= BATCH) return;
    int lane = threadIdx.x & 63;
    int cu = map[users[b]];
    int ci = map[items[b] + N_USERS];
    float aU = accU[b * 64 + lane] + l3[(size_t)cu * 64 + lane];
    float aI = accI[b * 64 + lane] + l3[(size_t)ci * 64 + lane];
    float p = aU * aI;
    for (int off = 32; off; off >>= 1) p += __shfl_xor(p, off);
    if (lane == 0) out[b] = p * (1.0f / 16.0f);  // (acc/4)·(acc/4)
}

// ---------------- launch ----------------

extern "C" void kernel_launch(void* const* d_in, const int* in_sizes, int n_in,
                              void* d_out, int out_size, void* d_ws, size_t ws_size,
                              hipStream_t stream) {
    const float* user_emb = (const float*)d_in[0];
    const float* item_emb = (const float*)d_in[1];
    const float* vals = (const float*)d_in[2];
    const int* src = (const int*)d_in[3];
    const int* dst = (const int*)d_in[4];
    const int* users = (const int*)d_in[5];
    const int* items = (const int*)d_in[6];
    float* out = (float*)d_out;

    char* ws = (char*)d_ws;
    size_t off = 0;
    auto alloc = [&](size_t bytes) {
        char* p = ws + off;
        off += (bytes + 255) & ~(size_t)255;
        return p;
    };
    ushort* ebf0 = (ushort*)alloc((size_t)N_NODES * DIM * 2);  // 19.2 MB bf16 concat tables
    ushort* ebf1 = (ushort*)alloc((size_t)N_NODES * DIM * 2);  // layer-1 out (aliases tmp lo)
    ushort* ebf2 = (ushort*)alloc((size_t)N_NODES * DIM * 2);  // layer-2 out (aliases tmp hi)
    int2* fin = (int2*)alloc((size_t)N_EDGES * 8);             // 32 MB dense CSR records
    int* row_ptr = (int*)alloc((size_t)(N_NODES + 1) * 4);
    int* bucket_ptr = (int*)alloc((size_t)(NBKT + 1) * 4);
    int* gcur = (int*)alloc((size_t)NBKT * 4);
    int* map = (int*)alloc((size_t)N_NODES * 4);
    int* sdeg = (int*)alloc((size_t)2 * BATCH * 4);
    int* srow = (int*)alloc((size_t)(2 * BATCH + 1) * 4);
    int* sfill = (int*)alloc((size_t)2 * BATCH * 4);
    int* scnt = (int*)alloc(256);
    unsigned long long* slist = (unsigned long long*)alloc((size_t)SLIST_CAP * 8);
    int2* sfin = (int2*)alloc((size_t)SLIST_CAP * 8);
    float* l3 = (float*)alloc((size_t)2 * BATCH * DIM * 4);
    float* accU = (float*)alloc((size_t)BATCH * DIM * 4);
    float* accI = (float*)alloc((size_t)BATCH * DIM * 4);
    // 37.75 MB fixed-stride partition scratch aliases ebf1+ebf2 (38.4 MB contiguous);
    // tmp is dead after k_bsort, before ebf1/2 are first written.
    int2* tmp = (int2*)ebf1;

    hipMemsetAsync(map, 0xFF, (size_t)N_NODES * 4, stream);  // map = -1

    k_markcvt<<<(N_NODES * DIM / 4 + 255) / 256, 256, 0, stream>>>(
        user_emb, item_emb, ebf0, users, items, map, sdeg, sfill, gcur, scnt);

    int pa_blocks = (N_EDGES + PA_EDGES - 1) / PA_EDGES;
    k_partition<<<pa_blocks, 256, 0, stream>>>(src, dst, vals, map, gcur, tmp, sdeg, scnt, slist);
    k_scan2<<<2, 1024, 0, stream>>>(gcur, bucket_ptr, sdeg, srow);
    k_sscatter<<<SLIST_CAP / 256, 256, 0, stream>>>(slist, scnt, srow, sfill, sfin);
    k_bsort<<<NBKT, 512, 0, stream>>>(tmp, gcur, bucket_ptr, row_ptr, fin);

    int gb = (2 * BATCH * DIM + 255) / 256;
    int spmm_blocks = (N_NODES * 64 + 255) / 256;
    // layer 1: ebf0 -> ebf1, then fused layer-0 + layer-1 sampled accumulate
    k_spmm16<<<spmm_blocks, 256, 0, stream>>>(ebf0, ebf1, row_ptr, fin);
    k_gacc0<<<gb, 256, 0, stream>>>(user_emb, item_emb, ebf1, users, items, accU, accI);
    // layer 2: ebf1 -> ebf2
    k_spmm16<<<spmm_blocks, 256, 0, stream>>>(ebf1, ebf2, row_ptr, fin);
    k_gacc<<<gb, 256, 0, stream>>>(ebf2, users, items, accU, accI);
    // layer 3: sampled rows only -> l3
    k_samp<<<(2 * BATCH * 64 + 255) / 256, 256, 0, stream>>>(ebf2, srow, sfin, l3);

    k_dot<<<(BATCH * 64 + 255) / 256, 256, 0, stream>>>(accU, accI, l3, map, users, items, out);
}

// Round 2
// 382.205 us; speedup vs baseline: 1.0445x; 1.0402x over previous
//
#include <hip/hip_runtime.h>
#include <hip/hip_bf16.h>

#define N_USERS 100000
#define N_ITEMS 50000
#define N_NODES 150000
#define DIM 64
#define N_EDGES 4000000
#define BATCH 4096

#define NBKT 512
#define BW 294           // nodes per bucket; 512*294 = 150528 >= 150000
#define STRIDE 9216      // tmp records per bucket (mean 7840, sigma ~88 -> +15.6 sigma)
#define PA_EDGES 4096    // edges per partition block
#define PA_ITER 16       // edges per thread (register-cached)
#define SCAP 384         // sampled-edge staging slots per partition block (mean ~217)
#define SLIST_CAP 262144

// ---------------- bf16 helpers ----------------
__device__ __forceinline__ float blo(unsigned int u) { return __uint_as_float(u << 16); }
__device__ __forceinline__ float bhi(unsigned int u) { return __uint_as_float(u & 0xffff0000u); }
__device__ __forceinline__ unsigned int f2b(float f) {  // RTNE
    unsigned int x = __float_as_uint(f);
    return (x + 0x7fffu + ((x >> 16) & 1u)) >> 16;
}
__device__ __forceinline__ unsigned int pack2(float a, float b) {
    return f2b(a) | (f2b(b) << 16);
}

typedef float v2f __attribute__((ext_vector_type(2)));

// fp32 tables -> bf16 concat table, fused with sampled-node marking + counter init
__global__ void k_markcvt(const float* __restrict__ uemb, const float* __restrict__ iemb,
                          ushort* __restrict__ out, const int* __restrict__ users,
                          const int* __restrict__ items, int* __restrict__ map,
                          int* __restrict__ sdeg, int* __restrict__ sfill,
                          int* __restrict__ gcur, int* __restrict__ scnt) {
    int tid = blockIdx.x * blockDim.x + threadIdx.x;
    if (tid < 2 * BATCH) {
        sdeg[tid] = 0;
        sfill[tid] = 0;
        if (tid < NBKT) gcur[tid] = 0;
        if (tid == 0) scnt[0] = 0;
        if (tid < BATCH) map[users[tid]] = tid;          // dup race: any winner is canonical
        else map[items[tid - BATCH] + N_USERS] = tid;    // tid = BATCH + b
    }
    int i = tid * 4;
    if (i >= N_NODES * DIM) return;
    const float* srcp = (i < N_USERS * DIM) ? (uemb + i) : (iemb + (i - N_USERS * DIM));
    float4 v;
    v.x = __builtin_nontemporal_load(srcp + 0);
    v.y = __builtin_nontemporal_load(srcp + 1);
    v.z = __builtin_nontemporal_load(srcp + 2);
    v.w = __builtin_nontemporal_load(srcp + 3);
    *(uint2*)(out + i) = make_uint2(pack2(v.x, v.y), pack2(v.z, v.w));
}

// ---------------- two-pass register-cached partition + sampled-edge filter ----------------
// pass 1: edges -> registers, LDS histogram; reserve per-bin global runs; pass 2: scatter
// from registers into reserved runs (per-block ~128B runs per bin -> L2 write-combines).
__global__ void __launch_bounds__(256, 4) k_partition(
        const int* __restrict__ src, const int* __restrict__ dst,
        const float* __restrict__ vals, const int* __restrict__ map,
        int* __restrict__ gcur, int2* __restrict__ tmp,
        int* __restrict__ sdeg, int* __restrict__ scnt,
        unsigned long long* __restrict__ slist) {
    __shared__ int cnt[NBKT];     // pass-1 histogram, then reused as pass-2 cursor
    __shared__ int base_s[NBKT];  // reserved global run base per bin
    __shared__ unsigned long long sbuf[SCAP];  // sampled-edge staging
    __shared__ int scnt_s, sbase_s;
    int t = threadIdx.x;
    for (int i = t; i < NBKT; i += 256) cnt[i] = 0;
    if (t == 0) scnt_s = 0;
    __syncthreads();
    size_t base = (size_t)blockIdx.x * PA_EDGES;
    int myb[PA_ITER];
    int mykey[PA_ITER];
    int myval[PA_ITER];
#pragma unroll
    for (int it = 0; it < PA_ITER; it++) {
        size_t i = base + (size_t)it * 256 + t;
        myb[it] = -1;
        if (i < N_EDGES) {
            int d = __builtin_nontemporal_load(dst + i);
            int s = __builtin_nontemporal_load(src + i);
            float v = __builtin_nontemporal_load(vals + i);
            int b = d / BW;
            int local = d - b * BW;
            myb[it] = b;
            mykey[it] = (s << 9) | local;
            myval[it] = __float_as_int(v);
            atomicAdd(&cnt[b], 1);
            int ms = map[d];
            if (ms >= 0) {  // edge feeds a sampled node's layer-3 row
                atomicAdd(&sdeg[ms], 1);
                unsigned long long pk = ((unsigned long long)(unsigned int)__float_as_int(v) << 32) |
                                        ((unsigned int)ms << 18) | (unsigned int)s;
                int sl = atomicAdd(&scnt_s, 1);
                if (sl < SCAP) sbuf[sl] = pk;
                else slist[atomicAdd(scnt, 1)] = pk;  // very rare
            }
        }
    }
    __syncthreads();
    // reserve global runs (one atomic per non-empty bin)
    for (int i = t; i < NBKT; i += 256) {
        int c = cnt[i];
        base_s[i] = (c > 0) ? atomicAdd(&gcur[i], c) : 0;
    }
    if (t == 0) {
        int c = min(scnt_s, SCAP);
        sbase_s = (c > 0) ? atomicAdd(scnt, c) : 0;
    }
    __syncthreads();
    for (int i = t; i < NBKT; i += 256) cnt[i] = 0;  // reuse as cursor
    __syncthreads();
    // drain sampled staging (coalesced)
    int stot = min(scnt_s, SCAP);
    for (int i = t; i < stot; i += 256) slist[sbase_s + i] = sbuf[i];
    // pass 2: scatter records from registers into reserved runs
#pragma unroll
    for (int it = 0; it < PA_ITER; it++) {
        int b = myb[it];
        if (b >= 0) {
            int pos = base_s[b] + atomicAdd(&cnt[b], 1);
            tmp[(size_t)b * STRIDE + pos] = make_int2(mykey[it], myval[it]);
        }
    }
}

// fused scans: block 0 = bucket scan (gcur -> bucket_ptr), block 1 = sampled scan (sdeg -> srow)
__global__ void k_scan2(const int* __restrict__ gcur, int* __restrict__ bucket_ptr,
                        const int* __restrict__ sdeg, int* __restrict__ srow) {
    __shared__ int ws[16];
    int t = threadIdx.x;  // 1024
    if (blockIdx.x == 0) {
        if (t >= 64) return;
        int lane = t;
        int carry = 0;
        for (int c = 0; c < NBKT / 64; c++) {
            int i = c * 64 + lane;
            int x = gcur[i];
            int incl = x;
            for (int off = 1; off < 64; off <<= 1) {
                int y = __shfl_up(incl, off);
                if (lane >= off) incl += y;
            }
            bucket_ptr[i] = carry + incl - x;
            carry += __shfl(incl, 63);
        }
        if (lane == 0) bucket_ptr[NBKT] = N_EDGES;
        return;
    }
    int v[8], p = 0;
#pragma unroll
    for (int j = 0; j < 8; j++) { v[j] = sdeg[t * 8 + j]; p += v[j]; }
    int lane = t & 63, w = t >> 6;
    int incl = p;
    for (int o = 1; o < 64; o <<= 1) {
        int y = __shfl_up(incl, o);
        if (lane >= o) incl += y;
    }
    if (lane == 63) ws[w] = incl;
    __syncthreads();
    int woff = 0;
    for (int j = 0; j < w; j++) woff += ws[j];
    int run = woff + incl - p;
#pragma unroll
    for (int j = 0; j < 8; j++) { srow[t * 8 + j] = run; run += v[j]; }
    if (t == 1023) srow[8192] = run;
}

// scatter sampled edges into slot-grouped sfin
__global__ void k_sscatter(const unsigned long long* __restrict__ slist,
                           const int* __restrict__ scnt, const int* __restrict__ srow,
                           int* __restrict__ sfill, int2* __restrict__ sfin) {
    int i = blockIdx.x * blockDim.x + threadIdx.x;
    if (i >= scnt[0]) return;
    unsigned long long pk = slist[i];
    int s = (int)(pk & 0x3FFFFu);
    int slot = (int)((pk >> 18) & 8191u);
    int vbits = (int)(pk >> 32);
    int pos = srow[slot] + atomicAdd(&sfill[slot], 1);
    sfin[pos] = make_int2(s, vbits);
}

// ---------------- pass B: sort within bucket (LDS hist + scan), emit dense CSR ----------------
// plain tmp loads: each block re-reads its ~74 KB bucket twice; it fits L2, NT would evict
__global__ void k_bsort(const int2* __restrict__ tmp, const int* __restrict__ gcur,
                        const int* __restrict__ bucket_ptr, int* __restrict__ row_ptr,
                        int2* __restrict__ fin) {
    __shared__ int cnt[BW + 64];
    __shared__ int off[BW + 64];
    int b = blockIdx.x, t = threadIdx.x;  // 512 threads
    int node0 = b * BW;
    int nodes = min(BW, N_NODES - node0);  // may be negative for trailing empty buckets
    int gbase = bucket_ptr[b];
    int count = gcur[b];
    const int2* tb = tmp + (size_t)b * STRIDE;
    for (int i = t; i < BW + 64; i += 512) cnt[i] = 0;
    __syncthreads();
    for (int e = t; e < count; e += 512) atomicAdd(&cnt[tb[e].x & 511], 1);
    __syncthreads();
    if (t < 64) {
        int lane = t;
        int carry = 0;
        for (int c = 0; c < 5; c++) {
            int i = c * 64 + lane;
            int x = (i < nodes) ? cnt[i] : 0;
            int incl = x;
            for (int o = 1; o < 64; o <<= 1) {
                int y = __shfl_up(incl, o);
                if (lane >= o) incl += y;
            }
            if (i <= nodes) off[i] = carry + incl - x;
            carry += __shfl(incl, 63);
        }
    }
    __syncthreads();
    for (int i = t; i <= nodes; i += 512)
        if (node0 + i <= N_NODES) row_ptr[node0 + i] = gbase + off[i];
    __syncthreads();
    for (int e = t; e < count; e += 512) {
        int2 r = tb[e];
        int local = r.x & 511;
        int pos = gbase + atomicAdd(&off[local], 1);
        fin[pos] = make_int2(r.x >> 9, r.y);  // plain store: L2 write-combines the region
    }
}

// ---------------- bf16 SpMM: one wave per dst node, 8 groups x 8 lanes ----------------
// v3: single fully-predicated 32-edge burst (4 gathers in flight for EVERY node, not just
// deg>=33). Padding lanes clamp the record index to a line the wave already fetched and
// zero the weight -> ~20% padded FMAs bought with idle VALU slots, 2x deeper MLP.
// PLAIN fin loads / PLAIN eout store; NT variants regressed (R7/R8).

// one edge record: gather 16B of the src row, packed-FMA into 4x float2 accumulators
#define EDGE_FMA(r, u)                                                        \
    {                                                                         \
        float vf = __int_as_float((r).y);                                     \
        v2f vv = {vf, vf};                                                    \
        v2f f0 = {blo((u).x), bhi((u).x)};                                    \
        v2f f1 = {blo((u).y), bhi((u).y)};                                    \
        v2f f2 = {blo((u).z), bhi((u).z)};                                    \
        v2f f3 = {blo((u).w), bhi((u).w)};                                    \
        acc0 = __builtin_elementwise_fma(vv, f0, acc0);                       \
        acc1 = __builtin_elementwise_fma(vv, f1, acc1);                       \
        acc2 = __builtin_elementwise_fma(vv, f2, acc2);                       \
        acc3 = __builtin_elementwise_fma(vv, f3, acc3);                       \
    }

// 32-bit byte offsets: table is 19.2 MB, record arrays <= 32 MB -> SADDR + voffset form
#define GATHER16(basec, r) (*(const uint4*)((basec) + ((((unsigned int)(r).x) << 7) | qoff)))
#define REC8(basec, i) (*(const int2*)((basec) + (((unsigned int)(i)) << 3)))

// clamped 32-edge burst: all 4 rec loads + all 4 gathers issue before any FMA waits
#define BURST32(basec)                                                        \
    {                                                                         \
        int e1 = e + 8, e2 = e + 16, e3 = e + 24;                             \
        int2 ra = REC8(basec, e);                                             \
        int2 rb = REC8(basec, min(e1, last));                                 \
        int2 rc = REC8(basec, min(e2, last));                                 \
        int2 rd = REC8(basec, min(e3, last));                                 \
        rb.y = (e1 < end) ? rb.y : 0;                                         \
        rc.y = (e2 < end) ? rc.y : 0;                                         \
        rd.y = (e3 < end) ? rd.y : 0;                                         \
        uint4 ua = GATHER16(einc, ra);                                        \
        uint4 ub = GATHER16(einc, rb);                                        \
        uint4 uc = GATHER16(einc, rc);                                        \
        uint4 ud = GATHER16(einc, rd);                                        \
        EDGE_FMA(ra, ua);                                                     \
        EDGE_FMA(rb, ub);                                                     \
        EDGE_FMA(rc, uc);                                                     \
        EDGE_FMA(rd, ud);                                                     \
        e += 32;                                                              \
    }

__global__ void k_spmm16(const ushort* __restrict__ ein, ushort* __restrict__ eout,
                         const int* __restrict__ row_ptr, const int2* __restrict__ fin) {
    int wave = (blockIdx.x * blockDim.x + threadIdx.x) >> 6;
    if (wave >= N_NODES) return;
    int lane = threadIdx.x & 63;
    int g = lane >> 3;  // edge group 0..7
    int q = lane & 7;   // 8 bf16 dims per lane
    unsigned int qoff = (unsigned int)q << 4;
    const char* einc = (const char*)ein;
    const char* finc = (const char*)fin;
    int start = row_ptr[wave], end = row_ptr[wave + 1];
    int last = max(start, end - 1);  // safe clamp target (>=0 even for empty head rows)
    v2f acc0 = {0.f, 0.f}, acc1 = {0.f, 0.f}, acc2 = {0.f, 0.f}, acc3 = {0.f, 0.f};
    int e = start + g;
    // deg <= 32 (87% of nodes): exactly one burst; rare high-degree nodes loop
    while (e < end) BURST32(finc);
#pragma unroll
    for (int off = 8; off < 64; off <<= 1) {
        acc0.x += __shfl_xor(acc0.x, off);
        acc0.y += __shfl_xor(acc0.y, off);
        acc1.x += __shfl_xor(acc1.x, off);
        acc1.y += __shfl_xor(acc1.y, off);
        acc2.x += __shfl_xor(acc2.x, off);
        acc2.y += __shfl_xor(acc2.y, off);
        acc3.x += __shfl_xor(acc3.x, off);
        acc3.y += __shfl_xor(acc3.y, off);
    }
    if (lane < 8) {
        uint4 p;
        p.x = pack2(acc0.x, acc0.y);
        p.y = pack2(acc1.x, acc1.y);
        p.z = pack2(acc2.x, acc2.y);
        p.w = pack2(acc3.x, acc3.y);
        *(uint4*)(eout + (size_t)wave * DIM + q * 8) = p;
    }
}

// layer-3 at sampled slots only -> l3 (overwrite; zero rows for empty slots)
__global__ void k_samp(const ushort* __restrict__ ein, const int* __restrict__ srow,
                       const int2* __restrict__ sfin, float* __restrict__ l3) {
    int slot = (blockIdx.x * blockDim.x + threadIdx.x) >> 6;
    if (slot >= 2 * BATCH) return;
    int lane = threadIdx.x & 63;
    int g = lane >> 3;
    int q = lane & 7;
    unsigned int qoff = (unsigned int)q << 4;
    const char* einc = (const char*)ein;
    const char* sfc = (const char*)sfin;
    int start = srow[slot], end = srow[slot + 1];
    int last = max(start, end - 1);
    v2f acc0 = {0.f, 0.f}, acc1 = {0.f, 0.f}, acc2 = {0.f, 0.f}, acc3 = {0.f, 0.f};
    int e = start + g;
    while (e < end) BURST32(sfc);
#pragma unroll
    for (int off = 8; off < 64; off <<= 1) {
        acc0.x += __shfl_xor(acc0.x, off);
        acc0.y += __shfl_xor(acc0.y, off);
        acc1.x += __shfl_xor(acc1.x, off);
        acc1.y += __shfl_xor(acc1.y, off);
        acc2.x += __shfl_xor(acc2.x, off);
        acc2.y += __shfl_xor(acc2.y, off);
        acc3.x += __shfl_xor(acc3.x, off);
        acc3.y += __shfl_xor(acc3.y, off);
    }
    if (lane < 8) {
        float* row = l3 + (size_t)slot * DIM + q * 8;
        *(float4*)row = make_float4(acc0.x, acc0.y, acc1.x, acc1.y);
        *(float4*)(row + 4) = make_float4(acc2.x, acc2.y, acc3.x, acc3.y);
    }
}

// layer-0 + layer-1: acc = fp32 table row + bf16 ebf1 row (fused, overwrite)
__global__ void k_gacc0(const float* __restrict__ uemb, const float* __restrict__ iemb,
                        const ushort* __restrict__ emb, const int* __restrict__ users,
                        const int* __restrict__ items, float* __restrict__ accU,
                        float* __restrict__ accI) {
    int i = blockIdx.x * blockDim.x + threadIdx.x;
    if (i >= 2 * BATCH * DIM) return;
    int j = (i < BATCH * DIM) ? i : i - BATCH * DIM;
    int b = j >> 6, l = j & 63;
    if (i < BATCH * DIM) {
        int n = users[b];
        unsigned int u = emb[(size_t)n * DIM + l];
        accU[j] = uemb[(size_t)n * DIM + l] + __uint_as_float(u << 16);
    } else {
        int n = items[b];
        unsigned int u = emb[(size_t)(n + N_USERS) * DIM + l];
        accI[j] = iemb[(size_t)n * DIM + l] + __uint_as_float(u << 16);
    }
}

// layer-2: accumulate both sample sets from bf16 table
__global__ void k_gacc(const ushort* __restrict__ emb, const int* __restrict__ users,
                       const int* __restrict__ items, float* __restrict__ accU,
                       float* __restrict__ accI) {
    int i = blockIdx.x * blockDim.x + threadIdx.x;
    if (i >= 2 * BATCH * DIM) return;
    int j = (i < BATCH * DIM) ? i : i - BATCH * DIM;
    int b = j >> 6, l = j & 63;
    if (i < BATCH * DIM) {
        unsigned int u = emb[(size_t)users[b] * DIM + l];
        accU[j] += __uint_as_float(u << 16);
    } else {
        unsigned int u = emb[(size_t)(items[b] + N_USERS) * DIM + l];
        accI[j] += __uint_as_float(u << 16);
    }
}

// final dot: (acc + l3[canonical slot]) pairs
__global__ void k_dot(const float* __restrict__ accU, const float* __restrict__ accI,
                      const float* __restrict__ l3, const int* __restrict__ map,
                      const int* __restrict__ users, const int* __restrict__ items,
                      float* __restrict__ out) {
    int b = (blockIdx.x * blockDim.x + threadIdx.x) >> 6;
    if (b >= BATCH) return;
    int lane = threadIdx.x & 63;
    int cu = map[users[b]];
    int ci = map[items[b] + N_USERS];
    float aU = accU[b * 64 + lane] + l3[(size_t)cu * 64 + lane];
    float aI = accI[b * 64 + lane] + l3[(size_t)ci * 64 + lane];
    float p = aU * aI;
    for (int off = 32; off; off >>= 1) p += __shfl_xor(p, off);
    if (lane == 0) out[b] = p * (1.0f / 16.0f);  // (acc/4)·(acc/4)
}

// ---------------- launch ----------------

extern "C" void kernel_launch(void* const* d_in, const int* in_sizes, int n_in,
                              void* d_out, int out_size, void* d_ws, size_t ws_size,
                              hipStream_t stream) {
    const float* user_emb = (const float*)d_in[0];
    const float* item_emb = (const float*)d_in[1];
    const float* vals = (const float*)d_in[2];
    const int* src = (const int*)d_in[3];
    const int* dst = (const int*)d_in[4];
    const int* users = (const int*)d_in[5];
    const int* items = (const int*)d_in[6];
    float* out = (float*)d_out;

    char* ws = (char*)d_ws;
    size_t off = 0;
    auto alloc = [&](size_t bytes) {
        char* p = ws + off;
        off += (bytes + 255) & ~(size_t)255;
        return p;
    };
    ushort* ebf0 = (ushort*)alloc((size_t)N_NODES * DIM * 2);  // 19.2 MB bf16 concat tables
    ushort* ebf1 = (ushort*)alloc((size_t)N_NODES * DIM * 2);  // layer-1 out (aliases tmp lo)
    ushort* ebf2 = (ushort*)alloc((size_t)N_NODES * DIM * 2);  // layer-2 out (aliases tmp hi)
    int2* fin = (int2*)alloc((size_t)N_EDGES * 8);             // 32 MB dense CSR records
    int* row_ptr = (int*)alloc((size_t)(N_NODES + 1) * 4);
    int* bucket_ptr = (int*)alloc((size_t)(NBKT + 1) * 4);
    int* gcur = (int*)alloc((size_t)NBKT * 4);
    int* map = (int*)alloc((size_t)N_NODES * 4);
    int* sdeg = (int*)alloc((size_t)2 * BATCH * 4);
    int* srow = (int*)alloc((size_t)(2 * BATCH + 1) * 4);
    int* sfill = (int*)alloc((size_t)2 * BATCH * 4);
    int* scnt = (int*)alloc(256);
    unsigned long long* slist = (unsigned long long*)alloc((size_t)SLIST_CAP * 8);
    int2* sfin = (int2*)alloc((size_t)SLIST_CAP * 8);
    float* l3 = (float*)alloc((size_t)2 * BATCH * DIM * 4);
    float* accU = (float*)alloc((size_t)BATCH * DIM * 4);
    float* accI = (float*)alloc((size_t)BATCH * DIM * 4);
    // 37.75 MB fixed-stride partition scratch aliases ebf1+ebf2 (38.4 MB contiguous);
    // tmp is dead after k_bsort, before ebf1/2 are first written.
    int2* tmp = (int2*)ebf1;

    hipMemsetAsync(map, 0xFF, (size_t)N_NODES * 4, stream);  // map = -1

    k_markcvt<<<(N_NODES * DIM / 4 + 255) / 256, 256, 0, stream>>>(
        user_emb, item_emb, ebf0, users, items, map, sdeg, sfill, gcur, scnt);

    int pa_blocks = (N_EDGES + PA_EDGES - 1) / PA_EDGES;
    k_partition<<<pa_blocks, 256, 0, stream>>>(src, dst, vals, map, gcur, tmp, sdeg, scnt, slist);
    k_scan2<<<2, 1024, 0, stream>>>(gcur, bucket_ptr, sdeg, srow);
    k_sscatter<<<SLIST_CAP / 256, 256, 0, stream>>>(slist, scnt, srow, sfill, sfin);
    k_bsort<<<NBKT, 512, 0, stream>>>(tmp, gcur, bucket_ptr, row_ptr, fin);

    int gb = (2 * BATCH * DIM + 255) / 256;
    int spmm_blocks = (N_NODES * 64 + 255) / 256;
    // layer 1: ebf0 -> ebf1, then fused layer-0 + layer-1 sampled accumulate
    k_spmm16<<<spmm_blocks, 256, 0, stream>>>(ebf0, ebf1, row_ptr, fin);
    k_gacc0<<<gb, 256, 0, stream>>>(user_emb, item_emb, ebf1, users, items, accU, accI);
    // layer 2: ebf1 -> ebf2
    k_spmm16<<<spmm_blocks, 256, 0, stream>>>(ebf1, ebf2, row_ptr, fin);
    k_gacc<<<gb, 256, 0, stream>>>(ebf2, users, items, accU, accI);
    // layer 3: sampled rows only -> l3
    k_samp<<<(2 * BATCH * 64 + 255) / 256, 256, 0, stream>>>(ebf2, srow, sfin, l3);

    k_dot<<<(BATCH * 64 + 255) / 256, 256, 0, stream>>>(accU, accI, l3, map, users, items, out);
}

// Round 3
// 342.550 us; speedup vs baseline: 1.1655x; 1.1158x over previous
//
#include <hip/hip_runtime.h>
#include <hip/hip_bf16.h>

#define N_USERS 100000
#define N_ITEMS 50000
#define N_NODES 150000
#define DIM 64
#define N_EDGES 4000000
#define BATCH 4096

#define NBKT 512
#define BW 294           // nodes per bucket; 512*294 = 150528 >= 150000
#define STRIDE 9216      // tmp records per bucket (mean 7840, sigma ~88 -> +15.6 sigma)
#define PA_EDGES 4096    // edges per partition block
#define PA_ITER 16       // edges per thread (register-cached)

// ---------------- bf16 helpers ----------------
__device__ __forceinline__ float blo(unsigned int u) { return __uint_as_float(u << 16); }
__device__ __forceinline__ float bhi(unsigned int u) { return __uint_as_float(u & 0xffff0000u); }
__device__ __forceinline__ unsigned int f2b(float f) {  // RTNE
    unsigned int x = __float_as_uint(f);
    return (x + 0x7fffu + ((x >> 16) & 1u)) >> 16;
}
__device__ __forceinline__ unsigned int pack2(float a, float b) {
    return f2b(a) | (f2b(b) << 16);
}

typedef float v2f __attribute__((ext_vector_type(2)));

// fp32 tables -> bf16 concat table, fused with bucket-counter init
__global__ void k_markcvt(const float* __restrict__ uemb, const float* __restrict__ iemb,
                          ushort* __restrict__ out, int* __restrict__ gcur) {
    int tid = blockIdx.x * blockDim.x + threadIdx.x;
    if (tid < NBKT) gcur[tid] = 0;
    int i = tid * 4;
    if (i >= N_NODES * DIM) return;
    const float* srcp = (i < N_USERS * DIM) ? (uemb + i) : (iemb + (i - N_USERS * DIM));
    float4 v;
    v.x = __builtin_nontemporal_load(srcp + 0);
    v.y = __builtin_nontemporal_load(srcp + 1);
    v.z = __builtin_nontemporal_load(srcp + 2);
    v.w = __builtin_nontemporal_load(srcp + 3);
    *(uint2*)(out + i) = make_uint2(pack2(v.x, v.y), pack2(v.z, v.w));
}

// ---------------- two-pass register-cached partition, LDS-sorted writeout ----------------
// pass 1: edges -> registers, LDS histogram; block-local scan + per-bin global reserve;
// pass 2: scatter records into LDS in bin-sorted order, then linear readout so consecutive
// lanes write consecutive records of the same bin -> HW coalescer merges to ~8 lines/wave
// (was ~64 scattered lines/wave -> L2-transaction-bound, VALUBusy 5%, 17% HBM).
__global__ void __launch_bounds__(256, 4) k_partition(
        const int* __restrict__ src, const int* __restrict__ dst,
        const float* __restrict__ vals,
        int* __restrict__ gcur, int2* __restrict__ tmp) {
    __shared__ int cnt[NBKT];       // pass-1 histogram, then reused as pass-2 cursor
    __shared__ int base_s[NBKT];    // reserved global run base per bin
    __shared__ int off_s[NBKT];     // block-local exclusive scan of cnt
    __shared__ int2 rec_s[PA_EDGES];     // 32 KB bin-sorted records
    __shared__ ushort bin_s[PA_EDGES];   // 8 KB bin tag per sorted slot
    int t = threadIdx.x;
    for (int i = t; i < NBKT; i += 256) cnt[i] = 0;
    __syncthreads();
    size_t base = (size_t)blockIdx.x * PA_EDGES;
    int myb[PA_ITER];
    int mykey[PA_ITER];
    int myval[PA_ITER];
#pragma unroll
    for (int it = 0; it < PA_ITER; it++) {
        size_t i = base + (size_t)it * 256 + t;
        myb[it] = -1;
        if (i < N_EDGES) {
            int d = __builtin_nontemporal_load(dst + i);
            int s = __builtin_nontemporal_load(src + i);
            float v = __builtin_nontemporal_load(vals + i);
            int b = d / BW;
            int local = d - b * BW;
            myb[it] = b;
            mykey[it] = (s << 9) | local;
            myval[it] = __float_as_int(v);
            atomicAdd(&cnt[b], 1);
        }
    }
    __syncthreads();
    // reserve global runs (one atomic per non-empty bin)
    for (int i = t; i < NBKT; i += 256) {
        int c = cnt[i];
        base_s[i] = (c > 0) ? atomicAdd(&gcur[i], c) : 0;
    }
    // block-local exclusive scan of cnt -> off_s (single wave, 8 chunks of 64)
    if (t < 64) {
        int lane = t;
        int carry = 0;
        for (int c = 0; c < NBKT / 64; c++) {
            int i = c * 64 + lane;
            int x = cnt[i];
            int incl = x;
            for (int o = 1; o < 64; o <<= 1) {
                int y = __shfl_up(incl, o);
                if (lane >= o) incl += y;
            }
            off_s[i] = carry + incl - x;
            carry += __shfl(incl, 63);
        }
    }
    __syncthreads();
    for (int i = t; i < NBKT; i += 256) cnt[i] = 0;  // reuse as cursor
    __syncthreads();
    // pass 2a: scatter from registers into bin-sorted LDS slots
#pragma unroll
    for (int it = 0; it < PA_ITER; it++) {
        int b = myb[it];
        if (b >= 0) {
            int pos = off_s[b] + atomicAdd(&cnt[b], 1);
            rec_s[pos] = make_int2(mykey[it], myval[it]);
            bin_s[pos] = (ushort)b;
        }
    }
    __syncthreads();
    // pass 2b: linear readout -> coalesced global runs
    int nrec = off_s[NBKT - 1] + cnt[NBKT - 1];
    for (int i = t; i < nrec; i += 256) {
        int2 r = rec_s[i];
        int b = bin_s[i];
        tmp[(size_t)b * STRIDE + base_s[b] + (i - off_s[b])] = r;
    }
}

// bucket scan: gcur -> bucket_ptr (single block, 64 lanes)
__global__ void k_scan(const int* __restrict__ gcur, int* __restrict__ bucket_ptr) {
    int lane = threadIdx.x;  // 64
    int carry = 0;
    for (int c = 0; c < NBKT / 64; c++) {
        int i = c * 64 + lane;
        int x = gcur[i];
        int incl = x;
        for (int off = 1; off < 64; off <<= 1) {
            int y = __shfl_up(incl, off);
            if (lane >= off) incl += y;
        }
        bucket_ptr[i] = carry + incl - x;
        carry += __shfl(incl, 63);
    }
    if (lane == 0) bucket_ptr[NBKT] = N_EDGES;
}

// ---------------- pass B: sort within bucket (LDS hist + scan), emit dense CSR ----------------
// plain tmp loads: each block re-reads its ~74 KB bucket twice; it fits L2, NT would evict
__global__ void k_bsort(const int2* __restrict__ tmp, const int* __restrict__ gcur,
                        const int* __restrict__ bucket_ptr, int* __restrict__ row_ptr,
                        int2* __restrict__ fin) {
    __shared__ int cnt[BW + 64];
    __shared__ int off[BW + 64];
    int b = blockIdx.x, t = threadIdx.x;  // 512 threads
    int node0 = b * BW;
    int nodes = min(BW, N_NODES - node0);  // may be negative for trailing empty buckets
    int gbase = bucket_ptr[b];
    int count = gcur[b];
    const int2* tb = tmp + (size_t)b * STRIDE;
    for (int i = t; i < BW + 64; i += 512) cnt[i] = 0;
    __syncthreads();
    for (int e = t; e < count; e += 512) atomicAdd(&cnt[tb[e].x & 511], 1);
    __syncthreads();
    if (t < 64) {
        int lane = t;
        int carry = 0;
        for (int c = 0; c < 5; c++) {
            int i = c * 64 + lane;
            int x = (i < nodes) ? cnt[i] : 0;
            int incl = x;
            for (int o = 1; o < 64; o <<= 1) {
                int y = __shfl_up(incl, o);
                if (lane >= o) incl += y;
            }
            if (i <= nodes) off[i] = carry + incl - x;
            carry += __shfl(incl, 63);
        }
    }
    __syncthreads();
    for (int i = t; i <= nodes; i += 512)
        if (node0 + i <= N_NODES) row_ptr[node0 + i] = gbase + off[i];
    __syncthreads();
    for (int e = t; e < count; e += 512) {
        int2 r = tb[e];
        int local = r.x & 511;
        int pos = gbase + atomicAdd(&off[local], 1);
        fin[pos] = make_int2(r.x >> 9, r.y);  // plain store: L2 write-combines the region
    }
}

// ---------------- bf16 SpMM: one wave per dst node, 8 groups x 8 lanes ----------------
// single fully-predicated 32-edge burst (4 gathers in flight for EVERY node). Padding lanes
// clamp the record index to a line the wave already fetched and zero the weight.
// PLAIN fin loads / PLAIN eout store; NT variants regressed (R7/R8).

// one edge record: gather 16B of the src row, packed-FMA into 4x float2 accumulators
#define EDGE_FMA(r, u)                                                        \
    {                                                                         \
        float vf = __int_as_float((r).y);                                     \
        v2f vv = {vf, vf};                                                    \
        v2f f0 = {blo((u).x), bhi((u).x)};                                    \
        v2f f1 = {blo((u).y), bhi((u).y)};                                    \
        v2f f2 = {blo((u).z), bhi((u).z)};                                    \
        v2f f3 = {blo((u).w), bhi((u).w)};                                    \
        acc0 = __builtin_elementwise_fma(vv, f0, acc0);                       \
        acc1 = __builtin_elementwise_fma(vv, f1, acc1);                       \
        acc2 = __builtin_elementwise_fma(vv, f2, acc2);                       \
        acc3 = __builtin_elementwise_fma(vv, f3, acc3);                       \
    }

// 32-bit byte offsets: table is 19.2 MB, record arrays <= 32 MB -> SADDR + voffset form
#define GATHER16(basec, r) (*(const uint4*)((basec) + ((((unsigned int)(r).x) << 7) | qoff)))
#define REC8(basec, i) (*(const int2*)((basec) + (((unsigned int)(i)) << 3)))

// clamped 32-edge burst: all 4 rec loads + all 4 gathers issue before any FMA waits
#define BURST32(basec)                                                        \
    {                                                                         \
        int e1 = e + 8, e2 = e + 16, e3 = e + 24;                             \
        int2 ra = REC8(basec, e);                                             \
        int2 rb = REC8(basec, min(e1, last));                                 \
        int2 rc = REC8(basec, min(e2, last));                                 \
        int2 rd = REC8(basec, min(e3, last));                                 \
        rb.y = (e1 < end) ? rb.y : 0;                                         \
        rc.y = (e2 < end) ? rc.y : 0;                                         \
        rd.y = (e3 < end) ? rd.y : 0;                                         \
        uint4 ua = GATHER16(einc, ra);                                        \
        uint4 ub = GATHER16(einc, rb);                                        \
        uint4 uc = GATHER16(einc, rc);                                        \
        uint4 ud = GATHER16(einc, rd);                                        \
        EDGE_FMA(ra, ua);                                                     \
        EDGE_FMA(rb, ub);                                                     \
        EDGE_FMA(rc, uc);                                                     \
        EDGE_FMA(rd, ud);                                                     \
        e += 32;                                                              \
    }

__global__ void k_spmm16(const ushort* __restrict__ ein, ushort* __restrict__ eout,
                         const int* __restrict__ row_ptr, const int2* __restrict__ fin) {
    int wave = (blockIdx.x * blockDim.x + threadIdx.x) >> 6;
    if (wave >= N_NODES) return;
    int lane = threadIdx.x & 63;
    int g = lane >> 3;  // edge group 0..7
    int q = lane & 7;   // 8 bf16 dims per lane
    unsigned int qoff = (unsigned int)q << 4;
    const char* einc = (const char*)ein;
    const char* finc = (const char*)fin;
    int start = row_ptr[wave], end = row_ptr[wave + 1];
    int last = max(start, end - 1);  // safe clamp target (>=0 even for empty head rows)
    v2f acc0 = {0.f, 0.f}, acc1 = {0.f, 0.f}, acc2 = {0.f, 0.f}, acc3 = {0.f, 0.f};
    int e = start + g;
    // deg <= 32 (87% of nodes): exactly one burst; rare high-degree nodes loop
    while (e < end) BURST32(finc);
#pragma unroll
    for (int off = 8; off < 64; off <<= 1) {
        acc0.x += __shfl_xor(acc0.x, off);
        acc0.y += __shfl_xor(acc0.y, off);
        acc1.x += __shfl_xor(acc1.x, off);
        acc1.y += __shfl_xor(acc1.y, off);
        acc2.x += __shfl_xor(acc2.x, off);
        acc2.y += __shfl_xor(acc2.y, off);
        acc3.x += __shfl_xor(acc3.x, off);
        acc3.y += __shfl_xor(acc3.y, off);
    }
    if (lane < 8) {
        uint4 p;
        p.x = pack2(acc0.x, acc0.y);
        p.y = pack2(acc1.x, acc1.y);
        p.z = pack2(acc2.x, acc2.y);
        p.w = pack2(acc3.x, acc3.y);
        *(uint4*)(eout + (size_t)wave * DIM + q * 8) = p;
    }
}

// layer-3 at sampled slots only -> l3, reading the dense CSR directly (fin rows ARE the
// sampled rows; the old slist/sfin duplicate pipeline is deleted). Duplicated sample ids
// recompute bitwise-identical rows, so no canonicalization needed downstream.
__global__ void k_samp(const ushort* __restrict__ ein, const int* __restrict__ row_ptr,
                       const int2* __restrict__ fin, const int* __restrict__ users,
                       const int* __restrict__ items, float* __restrict__ l3) {
    int slot = (blockIdx.x * blockDim.x + threadIdx.x) >> 6;
    if (slot >= 2 * BATCH) return;
    int lane = threadIdx.x & 63;
    int g = lane >> 3;
    int q = lane & 7;
    unsigned int qoff = (unsigned int)q << 4;
    const char* einc = (const char*)ein;
    const char* finc = (const char*)fin;
    int node = (slot < BATCH) ? users[slot] : (items[slot - BATCH] + N_USERS);
    int start = row_ptr[node], end = row_ptr[node + 1];
    int last = max(start, end - 1);
    v2f acc0 = {0.f, 0.f}, acc1 = {0.f, 0.f}, acc2 = {0.f, 0.f}, acc3 = {0.f, 0.f};
    int e = start + g;
    while (e < end) BURST32(finc);
#pragma unroll
    for (int off = 8; off < 64; off <<= 1) {
        acc0.x += __shfl_xor(acc0.x, off);
        acc0.y += __shfl_xor(acc0.y, off);
        acc1.x += __shfl_xor(acc1.x, off);
        acc1.y += __shfl_xor(acc1.y, off);
        acc2.x += __shfl_xor(acc2.x, off);
        acc2.y += __shfl_xor(acc2.y, off);
        acc3.x += __shfl_xor(acc3.x, off);
        acc3.y += __shfl_xor(acc3.y, off);
    }
    if (lane < 8) {
        float* row = l3 + (size_t)slot * DIM + q * 8;
        *(float4*)row = make_float4(acc0.x, acc0.y, acc1.x, acc1.y);
        *(float4*)(row + 4) = make_float4(acc2.x, acc2.y, acc3.x, acc3.y);
    }
}

// layer-0 + layer-1: acc = fp32 table row + bf16 ebf1 row (fused, overwrite)
__global__ void k_gacc0(const float* __restrict__ uemb, const float* __restrict__ iemb,
                        const ushort* __restrict__ emb, const int* __restrict__ users,
                        const int* __restrict__ items, float* __restrict__ accU,
                        float* __restrict__ accI) {
    int i = blockIdx.x * blockDim.x + threadIdx.x;
    if (i >= 2 * BATCH * DIM) return;
    int j = (i < BATCH * DIM) ? i : i - BATCH * DIM;
    int b = j >> 6, l = j & 63;
    if (i < BATCH * DIM) {
        int n = users[b];
        unsigned int u = emb[(size_t)n * DIM + l];
        accU[j] = uemb[(size_t)n * DIM + l] + __uint_as_float(u << 16);
    } else {
        int n = items[b];
        unsigned int u = emb[(size_t)(n + N_USERS) * DIM + l];
        accI[j] = iemb[(size_t)n * DIM + l] + __uint_as_float(u << 16);
    }
}

// layer-2: accumulate both sample sets from bf16 table
__global__ void k_gacc(const ushort* __restrict__ emb, const int* __restrict__ users,
                       const int* __restrict__ items, float* __restrict__ accU,
                       float* __restrict__ accI) {
    int i = blockIdx.x * blockDim.x + threadIdx.x;
    if (i >= 2 * BATCH * DIM) return;
    int j = (i < BATCH * DIM) ? i : i - BATCH * DIM;
    int b = j >> 6, l = j & 63;
    if (i < BATCH * DIM) {
        unsigned int u = emb[(size_t)users[b] * DIM + l];
        accU[j] += __uint_as_float(u << 16);
    } else {
        unsigned int u = emb[(size_t)(items[b] + N_USERS) * DIM + l];
        accI[j] += __uint_as_float(u << 16);
    }
}

// final dot: (acc + l3[own slot]) pairs; user slot b, item slot BATCH+b
__global__ void k_dot(const float* __restrict__ accU, const float* __restrict__ accI,
                      const float* __restrict__ l3, float* __restrict__ out) {
    int b = (blockIdx.x * blockDim.x + threadIdx.x) >> 6;
    if (b >= BATCH) return;
    int lane = threadIdx.x & 63;
    float aU = accU[b * 64 + lane] + l3[(size_t)b * 64 + lane];
    float aI = accI[b * 64 + lane] + l3[(size_t)(BATCH + b) * 64 + lane];
    float p = aU * aI;
    for (int off = 32; off; off >>= 1) p += __shfl_xor(p, off);
    if (lane == 0) out[b] = p * (1.0f / 16.0f);  // (acc/4)·(acc/4)
}

// ---------------- launch ----------------

extern "C" void kernel_launch(void* const* d_in, const int* in_sizes, int n_in,
                              void* d_out, int out_size, void* d_ws, size_t ws_size,
                              hipStream_t stream) {
    const float* user_emb = (const float*)d_in[0];
    const float* item_emb = (const float*)d_in[1];
    const float* vals = (const float*)d_in[2];
    const int* src = (const int*)d_in[3];
    const int* dst = (const int*)d_in[4];
    const int* users = (const int*)d_in[5];
    const int* items = (const int*)d_in[6];
    float* out = (float*)d_out;

    char* ws = (char*)d_ws;
    size_t off = 0;
    auto alloc = [&](size_t bytes) {
        char* p = ws + off;
        off += (bytes + 255) & ~(size_t)255;
        return p;
    };
    ushort* ebf0 = (ushort*)alloc((size_t)N_NODES * DIM * 2);  // 19.2 MB bf16 concat tables
    ushort* ebf1 = (ushort*)alloc((size_t)N_NODES * DIM * 2);  // layer-1 out (aliases tmp lo)
    ushort* ebf2 = (ushort*)alloc((size_t)N_NODES * DIM * 2);  // layer-2 out (aliases tmp hi)
    int2* fin = (int2*)alloc((size_t)N_EDGES * 8);             // 32 MB dense CSR records
    int* row_ptr = (int*)alloc((size_t)(N_NODES + 1) * 4);
    int* bucket_ptr = (int*)alloc((size_t)(NBKT + 1) * 4);
    int* gcur = (int*)alloc((size_t)NBKT * 4);
    float* l3 = (float*)alloc((size_t)2 * BATCH * DIM * 4);
    float* accU = (float*)alloc((size_t)BATCH * DIM * 4);
    float* accI = (float*)alloc((size_t)BATCH * DIM * 4);
    // 37.75 MB fixed-stride partition scratch aliases ebf1+ebf2 (38.4 MB contiguous);
    // tmp is dead after k_bsort, before ebf1/2 are first written.
    int2* tmp = (int2*)ebf1;

    k_markcvt<<<(N_NODES * DIM / 4 + 255) / 256, 256, 0, stream>>>(
        user_emb, item_emb, ebf0, gcur);

    int pa_blocks = (N_EDGES + PA_EDGES - 1) / PA_EDGES;
    k_partition<<<pa_blocks, 256, 0, stream>>>(src, dst, vals, gcur, tmp);
    k_scan<<<1, 64, 0, stream>>>(gcur, bucket_ptr);
    k_bsort<<<NBKT, 512, 0, stream>>>(tmp, gcur, bucket_ptr, row_ptr, fin);

    int gb = (2 * BATCH * DIM + 255) / 256;
    int spmm_blocks = (N_NODES * 64 + 255) / 256;
    // layer 1: ebf0 -> ebf1, then fused layer-0 + layer-1 sampled accumulate
    k_spmm16<<<spmm_blocks, 256, 0, stream>>>(ebf0, ebf1, row_ptr, fin);
    k_gacc0<<<gb, 256, 0, stream>>>(user_emb, item_emb, ebf1, users, items, accU, accI);
    // layer 2: ebf1 -> ebf2
    k_spmm16<<<spmm_blocks, 256, 0, stream>>>(ebf1, ebf2, row_ptr, fin);
    k_gacc<<<gb, 256, 0, stream>>>(ebf2, users, items, accU, accI);
    // layer 3: sampled rows only, straight from the dense CSR
    k_samp<<<(2 * BATCH * 64 + 255) / 256, 256, 0, stream>>>(ebf2, row_ptr, fin, users, items, l3);

    k_dot<<<(BATCH * 64 + 255) / 256, 256, 0, stream>>>(accU, accI, l3, out);
}

// Round 5
// 338.945 us; speedup vs baseline: 1.1779x; 1.0106x over previous
//
#include <hip/hip_runtime.h>
#include <hip/hip_bf16.h>

#define N_USERS 100000
#define N_ITEMS 50000
#define N_NODES 150000
#define DIM 64
#define N_EDGES 4000000
#define BATCH 4096

#define NBKT 512
#define BW 294           // nodes per bucket; 512*294 = 150528 >= 150000
#define STRIDE 9216      // tmp records per bucket (mean 7840, sigma ~88 -> +15.6 sigma)
#define PA_EDGES 4096    // edges per partition block
#define PA_ITER 16       // edges per thread (register-cached)
#define PA_BLOCKS ((N_EDGES + PA_EDGES - 1) / PA_EDGES)   // 977
#define CVT_BLOCKS (N_NODES * DIM / 4 / 256)              // 9375 (exact)

// ---------------- bf16 helpers ----------------
__device__ __forceinline__ float blo(unsigned int u) { return __uint_as_float(u << 16); }
__device__ __forceinline__ float bhi(unsigned int u) { return __uint_as_float(u & 0xffff0000u); }
__device__ __forceinline__ unsigned int f2b(float f) {  // RTNE
    unsigned int x = __float_as_uint(f);
    return (x + 0x7fffu + ((x >> 16) & 1u)) >> 16;
}
__device__ __forceinline__ unsigned int pack2(float a, float b) {
    return f2b(a) | (f2b(b) << 16);
}

typedef float v2f __attribute__((ext_vector_type(2)));

// ---------------- fused: fp32->bf16 table convert + two-pass partition ----------------
// partition blocks [0, PA_BLOCKS) run the latency-bound edge partition; blocks
// [PA_BLOCKS, PA_BLOCKS+CVT_BLOCKS) stream-convert the tables. No mutual dependency;
// fusing overlaps the BW-streaming convert under the partition instead of serializing.
// gcur is zeroed by a hipMemsetAsync before this kernel (init inside would race the
// per-bin atomicAdd reserves). Branch is blockIdx-uniform -> no partial-barrier hazard.
__global__ void __launch_bounds__(256, 4) k_cvtpart(
        const float* __restrict__ uemb, const float* __restrict__ iemb,
        ushort* __restrict__ ebf0,
        const int* __restrict__ src, const int* __restrict__ dst,
        const float* __restrict__ vals,
        int* __restrict__ gcur, int2* __restrict__ tmp) {
    __shared__ int cnt[NBKT];       // pass-1 histogram, then reused as pass-2 cursor
    __shared__ int base_s[NBKT];    // reserved global run base per bin
    __shared__ int off_s[NBKT];     // block-local exclusive scan of cnt
    __shared__ int2 rec_s[PA_EDGES];     // 32 KB bin-sorted records
    __shared__ ushort bin_s[PA_EDGES];   // 8 KB bin tag per sorted slot
    int t = threadIdx.x;
    if (blockIdx.x >= PA_BLOCKS) {
        // ---- convert branch ----
        int tid = (blockIdx.x - PA_BLOCKS) * 256 + t;
        int i = tid * 4;
        if (i >= N_NODES * DIM) return;
        const float* srcp = (i < N_USERS * DIM) ? (uemb + i) : (iemb + (i - N_USERS * DIM));
        float4 v;
        v.x = __builtin_nontemporal_load(srcp + 0);
        v.y = __builtin_nontemporal_load(srcp + 1);
        v.z = __builtin_nontemporal_load(srcp + 2);
        v.w = __builtin_nontemporal_load(srcp + 3);
        *(uint2*)(ebf0 + i) = make_uint2(pack2(v.x, v.y), pack2(v.z, v.w));
        return;
    }
    // ---- partition branch ----
    for (int i = t; i < NBKT; i += 256) cnt[i] = 0;
    __syncthreads();
    size_t base = (size_t)blockIdx.x * PA_EDGES;
    int myb[PA_ITER];
    int mykey[PA_ITER];
    int myval[PA_ITER];
#pragma unroll
    for (int it = 0; it < PA_ITER; it++) {
        size_t i = base + (size_t)it * 256 + t;
        myb[it] = -1;
        if (i < N_EDGES) {
            int d = __builtin_nontemporal_load(dst + i);
            int s = __builtin_nontemporal_load(src + i);
            float v = __builtin_nontemporal_load(vals + i);
            int b = d / BW;
            int local = d - b * BW;
            myb[it] = b;
            mykey[it] = (s << 9) | local;
            myval[it] = __float_as_int(v);
            atomicAdd(&cnt[b], 1);
        }
    }
    __syncthreads();
    // reserve global runs (one atomic per non-empty bin)
    for (int i = t; i < NBKT; i += 256) {
        int c = cnt[i];
        base_s[i] = (c > 0) ? atomicAdd(&gcur[i], c) : 0;
    }
    // block-local exclusive scan of cnt -> off_s (single wave, 8 chunks of 64)
    if (t < 64) {
        int lane = t;
        int carry = 0;
        for (int c = 0; c < NBKT / 64; c++) {
            int i = c * 64 + lane;
            int x = cnt[i];
            int incl = x;
            for (int o = 1; o < 64; o <<= 1) {
                int y = __shfl_up(incl, o);
                if (lane >= o) incl += y;
            }
            off_s[i] = carry + incl - x;
            carry += __shfl(incl, 63);
        }
    }
    __syncthreads();
    for (int i = t; i < NBKT; i += 256) cnt[i] = 0;  // reuse as cursor
    __syncthreads();
    // pass 2a: scatter from registers into bin-sorted LDS slots
#pragma unroll
    for (int it = 0; it < PA_ITER; it++) {
        int b = myb[it];
        if (b >= 0) {
            int pos = off_s[b] + atomicAdd(&cnt[b], 1);
            rec_s[pos] = make_int2(mykey[it], myval[it]);
            bin_s[pos] = (ushort)b;
        }
    }
    __syncthreads();
    // pass 2b: linear readout -> coalesced global runs
    int nrec = off_s[NBKT - 1] + cnt[NBKT - 1];
    for (int i = t; i < nrec; i += 256) {
        int2 r = rec_s[i];
        int b = bin_s[i];
        tmp[(size_t)b * STRIDE + base_s[b] + (i - off_s[b])] = r;
    }
}

// ---------------- pass B: sort within bucket (LDS hist + scan), emit dense CSR ----------------
// plain tmp loads: each block re-reads its ~74 KB bucket twice; it fits L2, NT would evict.
// gbase (prefix over gcur) computed in-block: one 64-lane masked reduce over 2 KB (L2-hot).
__global__ void k_bsort(const int2* __restrict__ tmp, const int* __restrict__ gcur,
                        int* __restrict__ row_ptr, int2* __restrict__ fin) {
    __shared__ int cnt[BW + 64];
    __shared__ int off[BW + 64];
    __shared__ int gbase_s;
    int b = blockIdx.x, t = threadIdx.x;  // 512 threads
    int node0 = b * BW;
    int nodes = min(BW, N_NODES - node0);  // may be negative for trailing empty buckets
    int count = gcur[b];
    const int2* tb = tmp + (size_t)b * STRIDE;
    if (t < 64) {
        int ssum = 0;
#pragma unroll
        for (int j = 0; j < 8; j++) {
            int idx = t * 8 + j;
            if (idx < b) ssum += gcur[idx];
        }
        for (int o = 32; o; o >>= 1) ssum += __shfl_xor(ssum, o);
        if (t == 0) gbase_s = ssum;
    }
    for (int i = t; i < BW + 64; i += 512) cnt[i] = 0;
    __syncthreads();
    int gbase = gbase_s;
    for (int e = t; e < count; e += 512) atomicAdd(&cnt[tb[e].x & 511], 1);
    __syncthreads();
    if (t < 64) {
        int lane = t;
        int carry = 0;
        for (int c = 0; c < 5; c++) {
            int i = c * 64 + lane;
            int x = (i < nodes) ? cnt[i] : 0;
            int incl = x;
            for (int o = 1; o < 64; o <<= 1) {
                int y = __shfl_up(incl, o);
                if (lane >= o) incl += y;
            }
            if (i <= nodes) off[i] = carry + incl - x;
            carry += __shfl(incl, 63);
        }
    }
    __syncthreads();
    for (int i = t; i <= nodes; i += 512)
        if (node0 + i <= N_NODES) row_ptr[node0 + i] = gbase + off[i];
    __syncthreads();
    for (int e = t; e < count; e += 512) {
        int2 r = tb[e];
        int local = r.x & 511;
        int pos = gbase + atomicAdd(&off[local], 1);
        fin[pos] = make_int2(r.x >> 9, r.y);  // plain store: L2 write-combines the region
    }
}

// ---------------- bf16 SpMM: one wave per TWO dst nodes, 8 groups x 8 lanes ----------------
// v4: rows 2w and 2w+1 share a wave; each loop iteration issues 8 record loads + 8 row
// gathers before any FMA waits -> 8 misses in flight per wave (MLP-8 probe: R3's MLP-4
// gave only +13% over MLP-2, this discriminates latency-bound vs fabric-bound).
// Fully predicated (clamped index + zeroed weight) so degree skew between the paired rows
// only costs L1-hit re-reads. Epilogue: lanes 0..15 store 256 B contiguous (both rows).

// one edge record: gather 16B of the src row, packed-FMA into 4x float2 accumulators
#define EDGE_FMA(r, u, A0, A1, A2, A3)                                        \
    {                                                                         \
        float vf = __int_as_float((r).y);                                     \
        v2f vv = {vf, vf};                                                    \
        v2f f0 = {blo((u).x), bhi((u).x)};                                    \
        v2f f1 = {blo((u).y), bhi((u).y)};                                    \
        v2f f2 = {blo((u).z), bhi((u).z)};                                    \
        v2f f3 = {blo((u).w), bhi((u).w)};                                    \
        A0 = __builtin_elementwise_fma(vv, f0, A0);                           \
        A1 = __builtin_elementwise_fma(vv, f1, A1);                           \
        A2 = __builtin_elementwise_fma(vv, f2, A2);                           \
        A3 = __builtin_elementwise_fma(vv, f3, A3);                           \
    }

// 32-bit byte offsets: table is 19.2 MB, record arrays <= 32 MB -> SADDR + voffset form
#define GATHER16(basec, r) (*(const uint4*)((basec) + ((((unsigned int)(r).x) << 7) | qoff)))
#define REC8(basec, i) (*(const int2*)((basec) + (((unsigned int)(i)) << 3)))

__global__ void __launch_bounds__(256) k_spmm16(
        const ushort* __restrict__ ein, ushort* __restrict__ eout,
        const int* __restrict__ row_ptr, const int2* __restrict__ fin) {
    int wave = (blockIdx.x * blockDim.x + threadIdx.x) >> 6;
    if (wave >= N_NODES / 2) return;
    int lane = threadIdx.x & 63;
    int g = lane >> 3;  // edge group 0..7
    int q = lane & 7;   // 8 bf16 dims per lane
    unsigned int qoff = (unsigned int)q << 4;
    const char* einc = (const char*)ein;
    const char* finc = (const char*)fin;
    int n0 = wave * 2;
    int s0 = row_ptr[n0];
    int m0 = row_ptr[n0 + 1];  // end of row0 == start of row1 (dense CSR)
    int m1 = row_ptr[n0 + 2];
    int last0 = max(s0, m0 - 1);
    int last1 = max(m0, m1 - 1);
    v2f A0 = {0.f, 0.f}, A1 = {0.f, 0.f}, A2 = {0.f, 0.f}, A3 = {0.f, 0.f};
    v2f B0 = {0.f, 0.f}, B1 = {0.f, 0.f}, B2 = {0.f, 0.f}, B3 = {0.f, 0.f};
    int ea = s0 + g, eb = m0 + g;
    while (ea < m0 || eb < m1) {
        int2 ra0 = REC8(finc, min(ea, last0));
        int2 ra1 = REC8(finc, min(ea + 8, last0));
        int2 ra2 = REC8(finc, min(ea + 16, last0));
        int2 ra3 = REC8(finc, min(ea + 24, last0));
        int2 rb0 = REC8(finc, min(eb, last1));
        int2 rb1 = REC8(finc, min(eb + 8, last1));
        int2 rb2 = REC8(finc, min(eb + 16, last1));
        int2 rb3 = REC8(finc, min(eb + 24, last1));
        ra0.y = (ea < m0) ? ra0.y : 0;
        ra1.y = (ea + 8 < m0) ? ra1.y : 0;
        ra2.y = (ea + 16 < m0) ? ra2.y : 0;
        ra3.y = (ea + 24 < m0) ? ra3.y : 0;
        rb0.y = (eb < m1) ? rb0.y : 0;
        rb1.y = (eb + 8 < m1) ? rb1.y : 0;
        rb2.y = (eb + 16 < m1) ? rb2.y : 0;
        rb3.y = (eb + 24 < m1) ? rb3.y : 0;
        uint4 ua0 = GATHER16(einc, ra0);
        uint4 ua1 = GATHER16(einc, ra1);
        uint4 ua2 = GATHER16(einc, ra2);
        uint4 ua3 = GATHER16(einc, ra3);
        uint4 ub0 = GATHER16(einc, rb0);
        uint4 ub1 = GATHER16(einc, rb1);
        uint4 ub2 = GATHER16(einc, rb2);
        uint4 ub3 = GATHER16(einc, rb3);
        EDGE_FMA(ra0, ua0, A0, A1, A2, A3);
        EDGE_FMA(ra1, ua1, A0, A1, A2, A3);
        EDGE_FMA(ra2, ua2, A0, A1, A2, A3);
        EDGE_FMA(ra3, ua3, A0, A1, A2, A3);
        EDGE_FMA(rb0, ub0, B0, B1, B2, B3);
        EDGE_FMA(rb1, ub1, B0, B1, B2, B3);
        EDGE_FMA(rb2, ub2, B0, B1, B2, B3);
        EDGE_FMA(rb3, ub3, B0, B1, B2, B3);
        ea += 32;
        eb += 32;
    }
#pragma unroll
    for (int off = 8; off < 64; off <<= 1) {
        A0.x += __shfl_xor(A0.x, off);
        A0.y += __shfl_xor(A0.y, off);
        A1.x += __shfl_xor(A1.x, off);
        A1.y += __shfl_xor(A1.y, off);
        A2.x += __shfl_xor(A2.x, off);
        A2.y += __shfl_xor(A2.y, off);
        A3.x += __shfl_xor(A3.x, off);
        A3.y += __shfl_xor(A3.y, off);
        B0.x += __shfl_xor(B0.x, off);
        B0.y += __shfl_xor(B0.y, off);
        B1.x += __shfl_xor(B1.x, off);
        B1.y += __shfl_xor(B1.y, off);
        B2.x += __shfl_xor(B2.x, off);
        B2.y += __shfl_xor(B2.y, off);
        B3.x += __shfl_xor(B3.x, off);
        B3.y += __shfl_xor(B3.y, off);
    }
    if (lane < 16) {
        bool r0 = lane < 8;
        uint4 p;
        p.x = r0 ? pack2(A0.x, A0.y) : pack2(B0.x, B0.y);
        p.y = r0 ? pack2(A1.x, A1.y) : pack2(B1.x, B1.y);
        p.z = r0 ? pack2(A2.x, A2.y) : pack2(B2.x, B2.y);
        p.w = r0 ? pack2(A3.x, A3.y) : pack2(B3.x, B3.y);
        // lanes 0..15 cover rows n0,n0+1 -> 256 B fully contiguous store
        *(uint4*)(eout + (size_t)n0 * DIM + (size_t)(lane & 15) * 8) = p;
    }
}

// layer-3 at sampled slots only -> l3, reading the dense CSR directly. Duplicated sample
// ids recompute bitwise-identical rows, so no canonicalization needed downstream.
__global__ void k_samp(const ushort* __restrict__ ein, const int* __restrict__ row_ptr,
                       const int2* __restrict__ fin, const int* __restrict__ users,
                       const int* __restrict__ items, float* __restrict__ l3) {
    int slot = (blockIdx.x * blockDim.x + threadIdx.x) >> 6;
    if (slot >= 2 * BATCH) return;
    int lane = threadIdx.x & 63;
    int g = lane >> 3;
    int q = lane & 7;
    unsigned int qoff = (unsigned int)q << 4;
    const char* einc = (const char*)ein;
    const char* finc = (const char*)fin;
    int node = (slot < BATCH) ? users[slot] : (items[slot - BATCH] + N_USERS);
    int start = row_ptr[node], end = row_ptr[node + 1];
    int last = max(start, end - 1);
    v2f A0 = {0.f, 0.f}, A1 = {0.f, 0.f}, A2 = {0.f, 0.f}, A3 = {0.f, 0.f};
    int e = start + g;
    while (e < end) {
        int e1 = e + 8, e2 = e + 16, e3 = e + 24;
        int2 ra = REC8(finc, e);
        int2 rb = REC8(finc, min(e1, last));
        int2 rc = REC8(finc, min(e2, last));
        int2 rd = REC8(finc, min(e3, last));
        rb.y = (e1 < end) ? rb.y : 0;
        rc.y = (e2 < end) ? rc.y : 0;
        rd.y = (e3 < end) ? rd.y : 0;
        uint4 ua = GATHER16(einc, ra);
        uint4 ub = GATHER16(einc, rb);
        uint4 uc = GATHER16(einc, rc);
        uint4 ud = GATHER16(einc, rd);
        EDGE_FMA(ra, ua, A0, A1, A2, A3);
        EDGE_FMA(rb, ub, A0, A1, A2, A3);
        EDGE_FMA(rc, uc, A0, A1, A2, A3);
        EDGE_FMA(rd, ud, A0, A1, A2, A3);
        e += 32;
    }
#pragma unroll
    for (int off = 8; off < 64; off <<= 1) {
        A0.x += __shfl_xor(A0.x, off);
        A0.y += __shfl_xor(A0.y, off);
        A1.x += __shfl_xor(A1.x, off);
        A1.y += __shfl_xor(A1.y, off);
        A2.x += __shfl_xor(A2.x, off);
        A2.y += __shfl_xor(A2.y, off);
        A3.x += __shfl_xor(A3.x, off);
        A3.y += __shfl_xor(A3.y, off);
    }
    if (lane < 8) {
        float* row = l3 + (size_t)slot * DIM + q * 8;
        *(float4*)row = make_float4(A0.x, A0.y, A1.x, A1.y);
        *(float4*)(row + 4) = make_float4(A2.x, A2.y, A3.x, A3.y);
    }
}

// layer-0 + layer-1: acc = fp32 table row + bf16 ebf1 row (fused, overwrite)
__global__ void k_gacc0(const float* __restrict__ uemb, const float* __restrict__ iemb,
                        const ushort* __restrict__ emb, const int* __restrict__ users,
                        const int* __restrict__ items, float* __restrict__ accU,
                        float* __restrict__ accI) {
    int i = blockIdx.x * blockDim.x + threadIdx.x;
    if (i >= 2 * BATCH * DIM) return;
    int j = (i < BATCH * DIM) ? i : i - BATCH * DIM;
    int b = j >> 6, l = j & 63;
    if (i < BATCH * DIM) {
        int n = users[b];
        unsigned int u = emb[(size_t)n * DIM + l];
        accU[j] = uemb[(size_t)n * DIM + l] + __uint_as_float(u << 16);
    } else {
        int n = items[b];
        unsigned int u = emb[(size_t)(n + N_USERS) * DIM + l];
        accI[j] = iemb[(size_t)n * DIM + l] + __uint_as_float(u << 16);
    }
}

// layer-2: accumulate both sample sets from bf16 table
__global__ void k_gacc(const ushort* __restrict__ emb, const int* __restrict__ users,
                       const int* __restrict__ items, float* __restrict__ accU,
                       float* __restrict__ accI) {
    int i = blockIdx.x * blockDim.x + threadIdx.x;
    if (i >= 2 * BATCH * DIM) return;
    int j = (i < BATCH * DIM) ? i : i - BATCH * DIM;
    int b = j >> 6, l = j & 63;
    if (i < BATCH * DIM) {
        unsigned int u = emb[(size_t)users[b] * DIM + l];
        accU[j] += __uint_as_float(u << 16);
    } else {
        unsigned int u = emb[(size_t)(items[b] + N_USERS) * DIM + l];
        accI[j] += __uint_as_float(u << 16);
    }
}

// final dot: (acc + l3[own slot]) pairs; user slot b, item slot BATCH+b
__global__ void k_dot(const float* __restrict__ accU, const float* __restrict__ accI,
                      const float* __restrict__ l3, float* __restrict__ out) {
    int b = (blockIdx.x * blockDim.x + threadIdx.x) >> 6;
    if (b >= BATCH) return;
    int lane = threadIdx.x & 63;
    float aU = accU[b * 64 + lane] + l3[(size_t)b * 64 + lane];
    float aI = accI[b * 64 + lane] + l3[(size_t)(BATCH + b) * 64 + lane];
    float p = aU * aI;
    for (int off = 32; off; off >>= 1) p += __shfl_xor(p, off);
    if (lane == 0) out[b] = p * (1.0f / 16.0f);  // (acc/4)·(acc/4)
}

// ---------------- launch ----------------

extern "C" void kernel_launch(void* const* d_in, const int* in_sizes, int n_in,
                              void* d_out, int out_size, void* d_ws, size_t ws_size,
                              hipStream_t stream) {
    const float* user_emb = (const float*)d_in[0];
    const float* item_emb = (const float*)d_in[1];
    const float* vals = (const float*)d_in[2];
    const int* src = (const int*)d_in[3];
    const int* dst = (const int*)d_in[4];
    const int* users = (const int*)d_in[5];
    const int* items = (const int*)d_in[6];
    float* out = (float*)d_out;

    char* ws = (char*)d_ws;
    size_t off = 0;
    auto alloc = [&](size_t bytes) {
        char* p = ws + off;
        off += (bytes + 255) & ~(size_t)255;
        return p;
    };
    ushort* ebf0 = (ushort*)alloc((size_t)N_NODES * DIM * 2);  // 19.2 MB bf16 concat tables
    ushort* ebf1 = (ushort*)alloc((size_t)N_NODES * DIM * 2);  // layer-1 out (aliases tmp lo)
    ushort* ebf2 = (ushort*)alloc((size_t)N_NODES * DIM * 2);  // layer-2 out (aliases tmp hi)
    int2* fin = (int2*)alloc((size_t)N_EDGES * 8);             // 32 MB dense CSR records
    int* row_ptr = (int*)alloc((size_t)(N_NODES + 1) * 4);
    int* gcur = (int*)alloc((size_t)NBKT * 4);
    float* l3 = (float*)alloc((size_t)2 * BATCH * DIM * 4);
    float* accU = (float*)alloc((size_t)BATCH * DIM * 4);
    float* accI = (float*)alloc((size_t)BATCH * DIM * 4);
    // 37.75 MB fixed-stride partition scratch aliases ebf1+ebf2 (38.4 MB contiguous);
    // tmp is dead after k_bsort, before ebf1/2 are first written.
    int2* tmp = (int2*)ebf1;

    hipMemsetAsync(gcur, 0, (size_t)NBKT * 4, stream);

    // fused convert + partition (independent workloads overlap on the machine)
    k_cvtpart<<<PA_BLOCKS + CVT_BLOCKS, 256, 0, stream>>>(
        user_emb, item_emb, ebf0, src, dst, vals, gcur, tmp);
    k_bsort<<<NBKT, 512, 0, stream>>>(tmp, gcur, row_ptr, fin);

    int gb = (2 * BATCH * DIM + 255) / 256;
    int spmm_blocks = (N_NODES / 2 * 64 + 255) / 256;  // one wave per 2 nodes
    // layer 1: ebf0 -> ebf1, then fused layer-0 + layer-1 sampled accumulate
    k_spmm16<<<spmm_blocks, 256, 0, stream>>>(ebf0, ebf1, row_ptr, fin);
    k_gacc0<<<gb, 256, 0, stream>>>(user_emb, item_emb, ebf1, users, items, accU, accI);
    // layer 2: ebf1 -> ebf2
    k_spmm16<<<spmm_blocks, 256, 0, stream>>>(ebf1, ebf2, row_ptr, fin);
    k_gacc<<<gb, 256, 0, stream>>>(ebf2, users, items, accU, accI);
    // layer 3: sampled rows only, straight from the dense CSR
    k_samp<<<(2 * BATCH * 64 + 255) / 256, 256, 0, stream>>>(ebf2, row_ptr, fin, users, items, l3);

    k_dot<<<(BATCH * 64 + 255) / 256, 256, 0, stream>>>(accU, accI, l3, out);
}

// Round 6
// 327.191 us; speedup vs baseline: 1.2202x; 1.0359x over previous
//
#include <hip/hip_runtime.h>
#include <hip/hip_bf16.h>

#define N_USERS 100000
#define N_ITEMS 50000
#define N_NODES 150000
#define DIM 64
#define N_EDGES 4000000
#define BATCH 4096

#define NBKT 512
#define BW 294           // nodes per bucket; 512*294 = 150528 >= 150000
#define STRIDE 9216      // tmp records per bucket (mean 7840, sigma ~88 -> +15.6 sigma)
#define PA_EDGES 4096    // edges per partition block
#define PA_ITER 16       // edges per thread (register-cached)
#define PA_BLOCKS ((N_EDGES + PA_EDGES - 1) / PA_EDGES)   // 977
#define CVT_BLOCKS (N_NODES * DIM / 4 / 256)              // 9375 (exact)
#define BS_ITER 16       // bsort records per thread (register-cached); 16*512=8192, tail loop covers rest

// ---------------- bf16 helpers ----------------
__device__ __forceinline__ float blo(unsigned int u) { return __uint_as_float(u << 16); }
__device__ __forceinline__ float bhi(unsigned int u) { return __uint_as_float(u & 0xffff0000u); }
__device__ __forceinline__ unsigned int f2b(float f) {  // RTNE
    unsigned int x = __float_as_uint(f);
    return (x + 0x7fffu + ((x >> 16) & 1u)) >> 16;
}
__device__ __forceinline__ unsigned int pack2(float a, float b) {
    return f2b(a) | (f2b(b) << 16);
}

typedef float v2f __attribute__((ext_vector_type(2)));

// ---------------- fused: fp32->bf16 table convert + two-pass partition ----------------
// v6: batched load phase — all 48 NT loads issue before any use (R2 profile showed
// VGPR=36 -> compiler interleaved load/use -> 16 serialized HBM round-trips/thread,
// VALUBusy 5%). Arrays are loaded raw then converted in place (no extra registers).
__global__ void __launch_bounds__(256, 4) k_cvtpart(
        const float* __restrict__ uemb, const float* __restrict__ iemb,
        ushort* __restrict__ ebf0,
        const int* __restrict__ src, const int* __restrict__ dst,
        const float* __restrict__ vals,
        int* __restrict__ gcur, int2* __restrict__ tmp) {
    __shared__ int cnt[NBKT];       // pass-1 histogram, then reused as pass-2 cursor
    __shared__ int base_s[NBKT];    // reserved global run base per bin
    __shared__ int off_s[NBKT];     // block-local exclusive scan of cnt
    __shared__ int2 rec_s[PA_EDGES];     // 32 KB bin-sorted records
    __shared__ ushort bin_s[PA_EDGES];   // 8 KB bin tag per sorted slot
    int t = threadIdx.x;
    if (blockIdx.x >= PA_BLOCKS) {
        // ---- convert branch ----
        int tid = (blockIdx.x - PA_BLOCKS) * 256 + t;
        int i = tid * 4;
        if (i >= N_NODES * DIM) return;
        const float* srcp = (i < N_USERS * DIM) ? (uemb + i) : (iemb + (i - N_USERS * DIM));
        float4 v;
        v.x = __builtin_nontemporal_load(srcp + 0);
        v.y = __builtin_nontemporal_load(srcp + 1);
        v.z = __builtin_nontemporal_load(srcp + 2);
        v.w = __builtin_nontemporal_load(srcp + 3);
        *(uint2*)(ebf0 + i) = make_uint2(pack2(v.x, v.y), pack2(v.z, v.w));
        return;
    }
    // ---- partition branch ----
    int myb[PA_ITER];    // load: raw dst; process: bin (or -1)
    int mykey[PA_ITER];  // load: raw src; process: (s<<9)|local
    int myval[PA_ITER];  // raw value bits
    size_t base = (size_t)blockIdx.x * PA_EDGES;
    // batched load phase: all loads issue back-to-back, no dependent use in between
#pragma unroll
    for (int it = 0; it < PA_ITER; it++) {
        size_t i = base + (size_t)it * 256 + t;
        if (i < N_EDGES) {
            myb[it] = __builtin_nontemporal_load(dst + i);
            mykey[it] = __builtin_nontemporal_load(src + i);
            myval[it] = __float_as_int(__builtin_nontemporal_load(vals + i));
        } else {
            myb[it] = -1;
        }
    }
    for (int i = t; i < NBKT; i += 256) cnt[i] = 0;
    __syncthreads();
    // process phase: convert in place + histogram
#pragma unroll
    for (int it = 0; it < PA_ITER; it++) {
        int d = myb[it];
        if (d >= 0) {
            int b = d / BW;
            mykey[it] = (mykey[it] << 9) | (d - b * BW);
            myb[it] = b;
            atomicAdd(&cnt[b], 1);
        }
    }
    __syncthreads();
    // reserve global runs (one atomic per non-empty bin)
    for (int i = t; i < NBKT; i += 256) {
        int c = cnt[i];
        base_s[i] = (c > 0) ? atomicAdd(&gcur[i], c) : 0;
    }
    // block-local exclusive scan of cnt -> off_s (single wave, 8 chunks of 64)
    if (t < 64) {
        int lane = t;
        int carry = 0;
        for (int c = 0; c < NBKT / 64; c++) {
            int i = c * 64 + lane;
            int x = cnt[i];
            int incl = x;
            for (int o = 1; o < 64; o <<= 1) {
                int y = __shfl_up(incl, o);
                if (lane >= o) incl += y;
            }
            off_s[i] = carry + incl - x;
            carry += __shfl(incl, 63);
        }
    }
    __syncthreads();
    for (int i = t; i < NBKT; i += 256) cnt[i] = 0;  // reuse as cursor
    __syncthreads();
    // pass 2a: scatter from registers into bin-sorted LDS slots
#pragma unroll
    for (int it = 0; it < PA_ITER; it++) {
        int b = myb[it];
        if (b >= 0) {
            int pos = off_s[b] + atomicAdd(&cnt[b], 1);
            rec_s[pos] = make_int2(mykey[it], myval[it]);
            bin_s[pos] = (ushort)b;
        }
    }
    __syncthreads();
    // pass 2b: linear readout -> coalesced global runs
    int nrec = off_s[NBKT - 1] + cnt[NBKT - 1];
    for (int i = t; i < nrec; i += 256) {
        int2 r = rec_s[i];
        int b = bin_s[i];
        tmp[(size_t)b * STRIDE + base_s[b] + (i - off_s[b])] = r;
    }
}

// ---------------- pass B: sort within bucket (LDS hist + scan), emit dense CSR ----------------
// v6: bucket records register-cached ONCE at kernel start (loads overlap the gbase reduce);
// histogram + scatter both run from registers -> second 30 MB tmp read deleted, and the
// 16 dependent load->atomic round-trips collapse into one batched issue.
__global__ void k_bsort(const int2* __restrict__ tmp, const int* __restrict__ gcur,
                        int* __restrict__ row_ptr, int2* __restrict__ fin) {
    __shared__ int cnt[BW + 64];
    __shared__ int off[BW + 64];
    __shared__ int gbase_s;
    int b = blockIdx.x, t = threadIdx.x;  // 512 threads
    int node0 = b * BW;
    int nodes = min(BW, N_NODES - node0);  // may be negative for trailing empty buckets
    int count = gcur[b];
    const int2* tb = tmp + (size_t)b * STRIDE;
    // batched record load (sentinel .x=-1; real keys are >= 0)
    int2 myrec[BS_ITER];
#pragma unroll
    for (int it = 0; it < BS_ITER; it++) {
        int e = it * 512 + t;
        myrec[it] = (e < count) ? tb[e] : make_int2(-1, 0);
    }
    if (t < 64) {
        int ssum = 0;
#pragma unroll
        for (int j = 0; j < 8; j++) {
            int idx = t * 8 + j;
            if (idx < b) ssum += gcur[idx];
        }
        for (int o = 32; o; o >>= 1) ssum += __shfl_xor(ssum, o);
        if (t == 0) gbase_s = ssum;
    }
    for (int i = t; i < BW + 64; i += 512) cnt[i] = 0;
    __syncthreads();
    int gbase = gbase_s;
#pragma unroll
    for (int it = 0; it < BS_ITER; it++)
        if (myrec[it].x >= 0) atomicAdd(&cnt[myrec[it].x & 511], 1);
    for (int e = BS_ITER * 512 + t; e < count; e += 512)  // rare tail (count > 8192)
        atomicAdd(&cnt[tb[e].x & 511], 1);
    __syncthreads();
    if (t < 64) {
        int lane = t;
        int carry = 0;
        for (int c = 0; c < 5; c++) {
            int i = c * 64 + lane;
            int x = (i < nodes) ? cnt[i] : 0;
            int incl = x;
            for (int o = 1; o < 64; o <<= 1) {
                int y = __shfl_up(incl, o);
                if (lane >= o) incl += y;
            }
            if (i <= nodes) off[i] = carry + incl - x;
            carry += __shfl(incl, 63);
        }
    }
    __syncthreads();
    for (int i = t; i <= nodes; i += 512)
        if (node0 + i <= N_NODES) row_ptr[node0 + i] = gbase + off[i];
    __syncthreads();
#pragma unroll
    for (int it = 0; it < BS_ITER; it++) {
        int2 r = myrec[it];
        if (r.x >= 0) {
            int pos = gbase + atomicAdd(&off[r.x & 511], 1);
            fin[pos] = make_int2(r.x >> 9, r.y);  // plain store: L2 write-combines the region
        }
    }
    for (int e = BS_ITER * 512 + t; e < count; e += 512) {  // rare tail
        int2 r = tb[e];
        int pos = gbase + atomicAdd(&off[r.x & 511], 1);
        fin[pos] = make_int2(r.x >> 9, r.y);
    }
}

// ---------------- bf16 SpMM: one wave per dst node, 8 groups x 8 lanes ----------------
// R3 form (measured best: 67.2 us vs 68.1 for dual-row MLP8 — gather stream is at its
// ~3.6 TB/s concurrency plateau, more per-wave MLP is null). Single fully-predicated
// 32-edge burst, 4 gathers in flight per wave. PLAIN fin loads / PLAIN eout store.

// one edge record: gather 16B of the src row, packed-FMA into 4x float2 accumulators
#define EDGE_FMA(r, u, A0, A1, A2, A3)                                        \
    {                                                                         \
        float vf = __int_as_float((r).y);                                     \
        v2f vv = {vf, vf};                                                    \
        v2f f0 = {blo((u).x), bhi((u).x)};                                    \
        v2f f1 = {blo((u).y), bhi((u).y)};                                    \
        v2f f2 = {blo((u).z), bhi((u).z)};                                    \
        v2f f3 = {blo((u).w), bhi((u).w)};                                    \
        A0 = __builtin_elementwise_fma(vv, f0, A0);                           \
        A1 = __builtin_elementwise_fma(vv, f1, A1);                           \
        A2 = __builtin_elementwise_fma(vv, f2, A2);                           \
        A3 = __builtin_elementwise_fma(vv, f3, A3);                           \
    }

// 32-bit byte offsets: table is 19.2 MB, record arrays <= 32 MB -> SADDR + voffset form
#define GATHER16(basec, r) (*(const uint4*)((basec) + ((((unsigned int)(r).x) << 7) | qoff)))
#define REC8(basec, i) (*(const int2*)((basec) + (((unsigned int)(i)) << 3)))

// clamped 32-edge burst: all 4 rec loads + all 4 gathers issue before any FMA waits
#define BURST32(basec)                                                        \
    {                                                                         \
        int e1 = e + 8, e2 = e + 16, e3 = e + 24;                             \
        int2 ra = REC8(basec, e);                                             \
        int2 rb = REC8(basec, min(e1, last));                                 \
        int2 rc = REC8(basec, min(e2, last));                                 \
        int2 rd = REC8(basec, min(e3, last));                                 \
        rb.y = (e1 < end) ? rb.y : 0;                                         \
        rc.y = (e2 < end) ? rc.y : 0;                                         \
        rd.y = (e3 < end) ? rd.y : 0;                                         \
        uint4 ua = GATHER16(einc, ra);                                        \
        uint4 ub = GATHER16(einc, rb);                                        \
        uint4 uc = GATHER16(einc, rc);                                        \
        uint4 ud = GATHER16(einc, rd);                                        \
        EDGE_FMA(ra, ua, A0, A1, A2, A3);                                     \
        EDGE_FMA(rb, ub, A0, A1, A2, A3);                                     \
        EDGE_FMA(rc, uc, A0, A1, A2, A3);                                     \
        EDGE_FMA(rd, ud, A0, A1, A2, A3);                                     \
        e += 32;                                                              \
    }

__global__ void k_spmm16(const ushort* __restrict__ ein, ushort* __restrict__ eout,
                         const int* __restrict__ row_ptr, const int2* __restrict__ fin) {
    int wave = (blockIdx.x * blockDim.x + threadIdx.x) >> 6;
    if (wave >= N_NODES) return;
    int lane = threadIdx.x & 63;
    int g = lane >> 3;  // edge group 0..7
    int q = lane & 7;   // 8 bf16 dims per lane
    unsigned int qoff = (unsigned int)q << 4;
    const char* einc = (const char*)ein;
    const char* finc = (const char*)fin;
    int start = row_ptr[wave], end = row_ptr[wave + 1];
    int last = max(start, end - 1);  // safe clamp target (>=0 even for empty head rows)
    v2f A0 = {0.f, 0.f}, A1 = {0.f, 0.f}, A2 = {0.f, 0.f}, A3 = {0.f, 0.f};
    int e = start + g;
    // deg <= 32 (87% of nodes): exactly one burst; rare high-degree nodes loop
    while (e < end) BURST32(finc);
#pragma unroll
    for (int off = 8; off < 64; off <<= 1) {
        A0.x += __shfl_xor(A0.x, off);
        A0.y += __shfl_xor(A0.y, off);
        A1.x += __shfl_xor(A1.x, off);
        A1.y += __shfl_xor(A1.y, off);
        A2.x += __shfl_xor(A2.x, off);
        A2.y += __shfl_xor(A2.y, off);
        A3.x += __shfl_xor(A3.x, off);
        A3.y += __shfl_xor(A3.y, off);
    }
    if (lane < 8) {
        uint4 p;
        p.x = pack2(A0.x, A0.y);
        p.y = pack2(A1.x, A1.y);
        p.z = pack2(A2.x, A2.y);
        p.w = pack2(A3.x, A3.y);
        *(uint4*)(eout + (size_t)wave * DIM + q * 8) = p;
    }
}

// layer-3 at sampled slots only -> l3, reading the dense CSR directly. Duplicated sample
// ids recompute bitwise-identical rows, so no canonicalization needed downstream.
__global__ void k_samp(const ushort* __restrict__ ein, const int* __restrict__ row_ptr,
                       const int2* __restrict__ fin, const int* __restrict__ users,
                       const int* __restrict__ items, float* __restrict__ l3) {
    int slot = (blockIdx.x * blockDim.x + threadIdx.x) >> 6;
    if (slot >= 2 * BATCH) return;
    int lane = threadIdx.x & 63;
    int g = lane >> 3;
    int q = lane & 7;
    unsigned int qoff = (unsigned int)q << 4;
    const char* einc = (const char*)ein;
    const char* finc = (const char*)fin;
    int node = (slot < BATCH) ? users[slot] : (items[slot - BATCH] + N_USERS);
    int start = row_ptr[node], end = row_ptr[node + 1];
    int last = max(start, end - 1);
    v2f A0 = {0.f, 0.f}, A1 = {0.f, 0.f}, A2 = {0.f, 0.f}, A3 = {0.f, 0.f};
    int e = start + g;
    while (e < end) BURST32(finc);
#pragma unroll
    for (int off = 8; off < 64; off <<= 1) {
        A0.x += __shfl_xor(A0.x, off);
        A0.y += __shfl_xor(A0.y, off);
        A1.x += __shfl_xor(A1.x, off);
        A1.y += __shfl_xor(A1.y, off);
        A2.x += __shfl_xor(A2.x, off);
        A2.y += __shfl_xor(A2.y, off);
        A3.x += __shfl_xor(A3.x, off);
        A3.y += __shfl_xor(A3.y, off);
    }
    if (lane < 8) {
        float* row = l3 + (size_t)slot * DIM + q * 8;
        *(float4*)row = make_float4(A0.x, A0.y, A1.x, A1.y);
        *(float4*)(row + 4) = make_float4(A2.x, A2.y, A3.x, A3.y);
    }
}

// layer-0 + layer-1: acc = fp32 table row + bf16 ebf1 row (fused, overwrite)
__global__ void k_gacc0(const float* __restrict__ uemb, const float* __restrict__ iemb,
                        const ushort* __restrict__ emb, const int* __restrict__ users,
                        const int* __restrict__ items, float* __restrict__ accU,
                        float* __restrict__ accI) {
    int i = blockIdx.x * blockDim.x + threadIdx.x;
    if (i >= 2 * BATCH * DIM) return;
    int j = (i < BATCH * DIM) ? i : i - BATCH * DIM;
    int b = j >> 6, l = j & 63;
    if (i < BATCH * DIM) {
        int n = users[b];
        unsigned int u = emb[(size_t)n * DIM + l];
        accU[j] = uemb[(size_t)n * DIM + l] + __uint_as_float(u << 16);
    } else {
        int n = items[b];
        unsigned int u = emb[(size_t)(n + N_USERS) * DIM + l];
        accI[j] = iemb[(size_t)n * DIM + l] + __uint_as_float(u << 16);
    }
}

// layer-2: accumulate both sample sets from bf16 table
__global__ void k_gacc(const ushort* __restrict__ emb, const int* __restrict__ users,
                       const int* __restrict__ items, float* __restrict__ accU,
                       float* __restrict__ accI) {
    int i = blockIdx.x * blockDim.x + threadIdx.x;
    if (i >= 2 * BATCH * DIM) return;
    int j = (i < BATCH * DIM) ? i : i - BATCH * DIM;
    int b = j >> 6, l = j & 63;
    if (i < BATCH * DIM) {
        unsigned int u = emb[(size_t)users[b] * DIM + l];
        accU[j] += __uint_as_float(u << 16);
    } else {
        unsigned int u = emb[(size_t)(items[b] + N_USERS) * DIM + l];
        accI[j] += __uint_as_float(u << 16);
    }
}

// final dot: (acc + l3[own slot]) pairs; user slot b, item slot BATCH+b
__global__ void k_dot(const float* __restrict__ accU, const float* __restrict__ accI,
                      const float* __restrict__ l3, float* __restrict__ out) {
    int b = (blockIdx.x * blockDim.x + threadIdx.x) >> 6;
    if (b >= BATCH) return;
    int lane = threadIdx.x & 63;
    float aU = accU[b * 64 + lane] + l3[(size_t)b * 64 + lane];
    float aI = accI[b * 64 + lane] + l3[(size_t)(BATCH + b) * 64 + lane];
    float p = aU * aI;
    for (int off = 32; off; off >>= 1) p += __shfl_xor(p, off);
    if (lane == 0) out[b] = p * (1.0f / 16.0f);  // (acc/4)·(acc/4)
}

// ---------------- launch ----------------

extern "C" void kernel_launch(void* const* d_in, const int* in_sizes, int n_in,
                              void* d_out, int out_size, void* d_ws, size_t ws_size,
                              hipStream_t stream) {
    const float* user_emb = (const float*)d_in[0];
    const float* item_emb = (const float*)d_in[1];
    const float* vals = (const float*)d_in[2];
    const int* src = (const int*)d_in[3];
    const int* dst = (const int*)d_in[4];
    const int* users = (const int*)d_in[5];
    const int* items = (const int*)d_in[6];
    float* out = (float*)d_out;

    char* ws = (char*)d_ws;
    size_t off = 0;
    auto alloc = [&](size_t bytes) {
        char* p = ws + off;
        off += (bytes + 255) & ~(size_t)255;
        return p;
    };
    ushort* ebf0 = (ushort*)alloc((size_t)N_NODES * DIM * 2);  // 19.2 MB bf16 concat tables
    ushort* ebf1 = (ushort*)alloc((size_t)N_NODES * DIM * 2);  // layer-1 out (aliases tmp lo)
    ushort* ebf2 = (ushort*)alloc((size_t)N_NODES * DIM * 2);  // layer-2 out (aliases tmp hi)
    int2* fin = (int2*)alloc((size_t)N_EDGES * 8);             // 32 MB dense CSR records
    int* row_ptr = (int*)alloc((size_t)(N_NODES + 1) * 4);
    int* gcur = (int*)alloc((size_t)NBKT * 4);
    float* l3 = (float*)alloc((size_t)2 * BATCH * DIM * 4);
    float* accU = (float*)alloc((size_t)BATCH * DIM * 4);
    float* accI = (float*)alloc((size_t)BATCH * DIM * 4);
    // 37.75 MB fixed-stride partition scratch aliases ebf1+ebf2 (38.4 MB contiguous);
    // tmp is dead after k_bsort, before ebf1/2 are first written.
    int2* tmp = (int2*)ebf1;

    hipMemsetAsync(gcur, 0, (size_t)NBKT * 4, stream);

    // fused convert + partition (independent workloads overlap on the machine)
    k_cvtpart<<<PA_BLOCKS + CVT_BLOCKS, 256, 0, stream>>>(
        user_emb, item_emb, ebf0, src, dst, vals, gcur, tmp);
    k_bsort<<<NBKT, 512, 0, stream>>>(tmp, gcur, row_ptr, fin);

    int gb = (2 * BATCH * DIM + 255) / 256;
    int spmm_blocks = (N_NODES * 64 + 255) / 256;  // one wave per node
    // layer 1: ebf0 -> ebf1, then fused layer-0 + layer-1 sampled accumulate
    k_spmm16<<<spmm_blocks, 256, 0, stream>>>(ebf0, ebf1, row_ptr, fin);
    k_gacc0<<<gb, 256, 0, stream>>>(user_emb, item_emb, ebf1, users, items, accU, accI);
    // layer 2: ebf1 -> ebf2
    k_spmm16<<<spmm_blocks, 256, 0, stream>>>(ebf1, ebf2, row_ptr, fin);
    k_gacc<<<gb, 256, 0, stream>>>(ebf2, users, items, accU, accI);
    // layer 3: sampled rows only, straight from the dense CSR
    k_samp<<<(2 * BATCH * 64 + 255) / 256, 256, 0, stream>>>(ebf2, row_ptr, fin, users, items, l3);

    k_dot<<<(BATCH * 64 + 255) / 256, 256, 0, stream>>>(accU, accI, l3, out);
}

// Round 7
// 310.599 us; speedup vs baseline: 1.2854x; 1.0534x over previous
//
#include <hip/hip_runtime.h>
#include <hip/hip_bf16.h>

#define N_USERS 100000
#define N_ITEMS 50000
#define N_NODES 150000
#define DIM 64
#define N_EDGES 4000000
#define BATCH 4096

#define NBKT 512
#define BW 294           // nodes per bucket; 512*294 = 150528 >= 150000
#define STRIDE 9216      // tmp records per bucket (mean 7840, sigma ~88 -> +15.6 sigma)
#define PA_EDGES 4096    // edges per partition block
#define PA_ITER 16       // edges per thread (register-cached)
#define PA_BLOCKS ((N_EDGES + PA_EDGES - 1) / PA_EDGES)   // 977
#define CVT_BLOCKS (N_NODES * DIM / 4 / 256)              // 9375 (exact)
#define BS_ITER 16       // bsort records per thread (register-cached); 16*512=8192, tail loop covers rest

// ---------------- bf16 helpers ----------------
__device__ __forceinline__ float blo(unsigned int u) { return __uint_as_float(u << 16); }
__device__ __forceinline__ float bhi(unsigned int u) { return __uint_as_float(u & 0xffff0000u); }
__device__ __forceinline__ unsigned int f2b(float f) {  // RTNE
    unsigned int x = __float_as_uint(f);
    return (x + 0x7fffu + ((x >> 16) & 1u)) >> 16;
}
__device__ __forceinline__ unsigned int pack2(float a, float b) {
    return f2b(a) | (f2b(b) << 16);
}

typedef float v2f __attribute__((ext_vector_type(2)));

// ---------------- fused: fp32->bf16 table convert + two-pass partition ----------------
// batched load phase: all 48 NT loads issue before any use (proven R6: +12 us vs
// interleaved load/use). LDS-sorted writeout -> coalesced per-bin global runs.
__global__ void __launch_bounds__(256, 4) k_cvtpart(
        const float* __restrict__ uemb, const float* __restrict__ iemb,
        ushort* __restrict__ ebf0,
        const int* __restrict__ src, const int* __restrict__ dst,
        const float* __restrict__ vals,
        int* __restrict__ gcur, int2* __restrict__ tmp) {
    __shared__ int cnt[NBKT];       // pass-1 histogram, then reused as pass-2 cursor
    __shared__ int base_s[NBKT];    // reserved global run base per bin
    __shared__ int off_s[NBKT];     // block-local exclusive scan of cnt
    __shared__ int2 rec_s[PA_EDGES];     // 32 KB bin-sorted records
    __shared__ ushort bin_s[PA_EDGES];   // 8 KB bin tag per sorted slot
    int t = threadIdx.x;
    if (blockIdx.x >= PA_BLOCKS) {
        // ---- convert branch ----
        int tid = (blockIdx.x - PA_BLOCKS) * 256 + t;
        int i = tid * 4;
        if (i >= N_NODES * DIM) return;
        const float* srcp = (i < N_USERS * DIM) ? (uemb + i) : (iemb + (i - N_USERS * DIM));
        float4 v;
        v.x = __builtin_nontemporal_load(srcp + 0);
        v.y = __builtin_nontemporal_load(srcp + 1);
        v.z = __builtin_nontemporal_load(srcp + 2);
        v.w = __builtin_nontemporal_load(srcp + 3);
        *(uint2*)(ebf0 + i) = make_uint2(pack2(v.x, v.y), pack2(v.z, v.w));
        return;
    }
    // ---- partition branch ----
    int myb[PA_ITER];    // load: raw dst; process: bin (or -1)
    int mykey[PA_ITER];  // load: raw src; process: (s<<9)|local
    int myval[PA_ITER];  // raw value bits
    size_t base = (size_t)blockIdx.x * PA_EDGES;
    // batched load phase: all loads issue back-to-back, no dependent use in between
#pragma unroll
    for (int it = 0; it < PA_ITER; it++) {
        size_t i = base + (size_t)it * 256 + t;
        if (i < N_EDGES) {
            myb[it] = __builtin_nontemporal_load(dst + i);
            mykey[it] = __builtin_nontemporal_load(src + i);
            myval[it] = __float_as_int(__builtin_nontemporal_load(vals + i));
        } else {
            myb[it] = -1;
        }
    }
    for (int i = t; i < NBKT; i += 256) cnt[i] = 0;
    __syncthreads();
    // process phase: convert in place + histogram
#pragma unroll
    for (int it = 0; it < PA_ITER; it++) {
        int d = myb[it];
        if (d >= 0) {
            int b = d / BW;
            mykey[it] = (mykey[it] << 9) | (d - b * BW);
            myb[it] = b;
            atomicAdd(&cnt[b], 1);
        }
    }
    __syncthreads();
    // reserve global runs (one atomic per non-empty bin)
    for (int i = t; i < NBKT; i += 256) {
        int c = cnt[i];
        base_s[i] = (c > 0) ? atomicAdd(&gcur[i], c) : 0;
    }
    // block-local exclusive scan of cnt -> off_s (single wave, 8 chunks of 64)
    if (t < 64) {
        int lane = t;
        int carry = 0;
        for (int c = 0; c < NBKT / 64; c++) {
            int i = c * 64 + lane;
            int x = cnt[i];
            int incl = x;
            for (int o = 1; o < 64; o <<= 1) {
                int y = __shfl_up(incl, o);
                if (lane >= o) incl += y;
            }
            off_s[i] = carry + incl - x;
            carry += __shfl(incl, 63);
        }
    }
    __syncthreads();
    for (int i = t; i < NBKT; i += 256) cnt[i] = 0;  // reuse as cursor
    __syncthreads();
    // pass 2a: scatter from registers into bin-sorted LDS slots
#pragma unroll
    for (int it = 0; it < PA_ITER; it++) {
        int b = myb[it];
        if (b >= 0) {
            int pos = off_s[b] + atomicAdd(&cnt[b], 1);
            rec_s[pos] = make_int2(mykey[it], myval[it]);
            bin_s[pos] = (ushort)b;
        }
    }
    __syncthreads();
    // pass 2b: linear readout -> coalesced global runs
    int nrec = off_s[NBKT - 1] + cnt[NBKT - 1];
    for (int i = t; i < nrec; i += 256) {
        int2 r = rec_s[i];
        int b = bin_s[i];
        tmp[(size_t)b * STRIDE + base_s[b] + (i - off_s[b])] = r;
    }
}

// ---------------- pass B: sort within bucket, emit dense CSR ----------------
// v7: LDS-staged writeout. The old register->global scatter put ~1 line transaction per
// 8 B record (R2's partition disease: WRITE_SIZE 2x payload, transaction-bound). Now
// records scatter into node-sorted DYNAMIC LDS (bucket <= 9216 rec = 73.7 KB), then a
// linear readout writes fin fully coalesced. Grid is 512 blocks = 2 blocks/CU, so the
// large LDS footprint costs no occupancy.
__global__ void k_bsort(const int2* __restrict__ tmp, const int* __restrict__ gcur,
                        int* __restrict__ row_ptr, int2* __restrict__ fin) {
    __shared__ int cnt[BW + 64];
    __shared__ int off[BW + 64];
    __shared__ int gbase_s;
    extern __shared__ int2 rec2[];  // STRIDE slots, node-sorted final records
    int b = blockIdx.x, t = threadIdx.x;  // 512 threads
    int node0 = b * BW;
    int nodes = min(BW, N_NODES - node0);  // may be negative for trailing empty buckets
    int count = gcur[b];
    const int2* tb = tmp + (size_t)b * STRIDE;
    // batched record load (sentinel .x=-1; real keys are >= 0)
    int2 myrec[BS_ITER];
#pragma unroll
    for (int it = 0; it < BS_ITER; it++) {
        int e = it * 512 + t;
        myrec[it] = (e < count) ? tb[e] : make_int2(-1, 0);
    }
    if (t < 64) {
        int ssum = 0;
#pragma unroll
        for (int j = 0; j < 8; j++) {
            int idx = t * 8 + j;
            if (idx < b) ssum += gcur[idx];
        }
        for (int o = 32; o; o >>= 1) ssum += __shfl_xor(ssum, o);
        if (t == 0) gbase_s = ssum;
    }
    for (int i = t; i < BW + 64; i += 512) cnt[i] = 0;
    __syncthreads();
    int gbase = gbase_s;
#pragma unroll
    for (int it = 0; it < BS_ITER; it++)
        if (myrec[it].x >= 0) atomicAdd(&cnt[myrec[it].x & 511], 1);
    for (int e = BS_ITER * 512 + t; e < count; e += 512)  // rare tail (count > 8192)
        atomicAdd(&cnt[tb[e].x & 511], 1);
    __syncthreads();
    if (t < 64) {
        int lane = t;
        int carry = 0;
        for (int c = 0; c < 5; c++) {
            int i = c * 64 + lane;
            int x = (i < nodes) ? cnt[i] : 0;
            int incl = x;
            for (int o = 1; o < 64; o <<= 1) {
                int y = __shfl_up(incl, o);
                if (lane >= o) incl += y;
            }
            if (i <= nodes) off[i] = carry + incl - x;
            carry += __shfl(incl, 63);
        }
    }
    __syncthreads();
    for (int i = t; i <= nodes; i += 512)
        if (node0 + i <= N_NODES) row_ptr[node0 + i] = gbase + off[i];
    __syncthreads();
    // scatter into node-sorted LDS (store final record form)
#pragma unroll
    for (int it = 0; it < BS_ITER; it++) {
        int2 r = myrec[it];
        if (r.x >= 0) {
            int pos = atomicAdd(&off[r.x & 511], 1);
            rec2[pos] = make_int2(r.x >> 9, r.y);
        }
    }
    for (int e = BS_ITER * 512 + t; e < count; e += 512) {  // rare tail
        int2 r = tb[e];
        int pos = atomicAdd(&off[r.x & 511], 1);
        rec2[pos] = make_int2(r.x >> 9, r.y);
    }
    __syncthreads();
    // linear readout -> fully coalesced fin writes
    for (int i = t; i < count; i += 512) fin[gbase + i] = rec2[i];
}

// ---------------- bf16 SpMM: one wave per dst node, 8 groups x 8 lanes ----------------
// Measured-best form (67.2 us; MLP-8 dual-row was null -> gather stream parked at its
// ~3.7 TB/s L2-miss/fabric plateau). Single fully-predicated 32-edge burst.

// one edge record: gather 16B of the src row, packed-FMA into 4x float2 accumulators
#define EDGE_FMA(r, u, A0, A1, A2, A3)                                        \
    {                                                                         \
        float vf = __int_as_float((r).y);                                     \
        v2f vv = {vf, vf};                                                    \
        v2f f0 = {blo((u).x), bhi((u).x)};                                    \
        v2f f1 = {blo((u).y), bhi((u).y)};                                    \
        v2f f2 = {blo((u).z), bhi((u).z)};                                    \
        v2f f3 = {blo((u).w), bhi((u).w)};                                    \
        A0 = __builtin_elementwise_fma(vv, f0, A0);                           \
        A1 = __builtin_elementwise_fma(vv, f1, A1);                           \
        A2 = __builtin_elementwise_fma(vv, f2, A2);                           \
        A3 = __builtin_elementwise_fma(vv, f3, A3);                           \
    }

// 32-bit byte offsets: table is 19.2 MB, record arrays <= 32 MB -> SADDR + voffset form
#define GATHER16(basec, r) (*(const uint4*)((basec) + ((((unsigned int)(r).x) << 7) | qoff)))
#define REC8(basec, i) (*(const int2*)((basec) + (((unsigned int)(i)) << 3)))

// clamped 32-edge burst: all 4 rec loads + all 4 gathers issue before any FMA waits
#define BURST32(basec, e, end, last, X0, X1, X2, X3)                          \
    {                                                                         \
        int e1 = (e) + 8, e2 = (e) + 16, e3 = (e) + 24;                       \
        int2 ra = REC8(basec, (e));                                           \
        int2 rb = REC8(basec, min(e1, last));                                 \
        int2 rc = REC8(basec, min(e2, last));                                 \
        int2 rd = REC8(basec, min(e3, last));                                 \
        rb.y = (e1 < (end)) ? rb.y : 0;                                       \
        rc.y = (e2 < (end)) ? rc.y : 0;                                       \
        rd.y = (e3 < (end)) ? rd.y : 0;                                       \
        uint4 ua = GATHER16(einc, ra);                                        \
        uint4 ub = GATHER16(einc, rb);                                        \
        uint4 uc = GATHER16(einc, rc);                                        \
        uint4 ud = GATHER16(einc, rd);                                        \
        EDGE_FMA(ra, ua, X0, X1, X2, X3);                                     \
        EDGE_FMA(rb, ub, X0, X1, X2, X3);                                     \
        EDGE_FMA(rc, uc, X0, X1, X2, X3);                                     \
        EDGE_FMA(rd, ud, X0, X1, X2, X3);                                     \
        (e) += 32;                                                            \
    }

__global__ void k_spmm16(const ushort* __restrict__ ein, ushort* __restrict__ eout,
                         const int* __restrict__ row_ptr, const int2* __restrict__ fin) {
    int wave = (blockIdx.x * blockDim.x + threadIdx.x) >> 6;
    if (wave >= N_NODES) return;
    int lane = threadIdx.x & 63;
    int g = lane >> 3;  // edge group 0..7
    int q = lane & 7;   // 8 bf16 dims per lane
    unsigned int qoff = (unsigned int)q << 4;
    const char* einc = (const char*)ein;
    const char* finc = (const char*)fin;
    int start = row_ptr[wave], end = row_ptr[wave + 1];
    int last = max(start, end - 1);  // safe clamp target (>=0 even for empty head rows)
    v2f A0 = {0.f, 0.f}, A1 = {0.f, 0.f}, A2 = {0.f, 0.f}, A3 = {0.f, 0.f};
    int e = start + g;
    // deg <= 32 (87% of nodes): exactly one burst; rare high-degree nodes loop
    while (e < end) BURST32(finc, e, end, last, A0, A1, A2, A3);
#pragma unroll
    for (int off = 8; off < 64; off <<= 1) {
        A0.x += __shfl_xor(A0.x, off);
        A0.y += __shfl_xor(A0.y, off);
        A1.x += __shfl_xor(A1.x, off);
        A1.y += __shfl_xor(A1.y, off);
        A2.x += __shfl_xor(A2.x, off);
        A2.y += __shfl_xor(A2.y, off);
        A3.x += __shfl_xor(A3.x, off);
        A3.y += __shfl_xor(A3.y, off);
    }
    if (lane < 8) {
        uint4 p;
        p.x = pack2(A0.x, A0.y);
        p.y = pack2(A1.x, A1.y);
        p.z = pack2(A2.x, A2.y);
        p.w = pack2(A3.x, A3.y);
        *(uint4*)(eout + (size_t)wave * DIM + q * 8) = p;
    }
}

// ---------------- fused sampled tail: layer-3 + layer accumulate + dot ----------------
// One wave per (user,item) pair. Replaces k_samp + k_gacc0 + k_gacc + k_dot (3 fewer
// launches, accU/accI/l3 buffers deleted). Layer-3 rows come straight from the dense CSR
// over ebf2; layers 0..2 are direct row reads (fp32 tables + ebf1 + ebf2). After the
// g-reduce every lane holds its q-block of the full row, so the dot is a per-lane 8-dim
// product + 3-step xor reduce.
__global__ void k_sampdot(const float* __restrict__ uemb, const float* __restrict__ iemb,
                          const ushort* __restrict__ ebf1, const ushort* __restrict__ ebf2,
                          const int* __restrict__ row_ptr, const int2* __restrict__ fin,
                          const int* __restrict__ users, const int* __restrict__ items,
                          float* __restrict__ out) {
    int b = (blockIdx.x * blockDim.x + threadIdx.x) >> 6;
    if (b >= BATCH) return;
    int lane = threadIdx.x & 63;
    int g = lane >> 3;
    int q = lane & 7;
    unsigned int qoff = (unsigned int)q << 4;
    const char* einc = (const char*)ebf2;  // layer-3 propagates from ebf2
    const char* finc = (const char*)fin;
    int iu = users[b];
    int ii = items[b];
    int nu = iu, ni = ii + N_USERS;
    // ---- user row ----
    v2f A0 = {0.f, 0.f}, A1 = {0.f, 0.f}, A2 = {0.f, 0.f}, A3 = {0.f, 0.f};
    {
        int start = row_ptr[nu], end = row_ptr[nu + 1];
        int last = max(start, end - 1);
        int e = start + g;
        while (e < end) BURST32(finc, e, end, last, A0, A1, A2, A3);
    }
    // ---- item row ----
    v2f B0 = {0.f, 0.f}, B1 = {0.f, 0.f}, B2 = {0.f, 0.f}, B3 = {0.f, 0.f};
    {
        int start = row_ptr[ni], end = row_ptr[ni + 1];
        int last = max(start, end - 1);
        int e = start + g;
        while (e < end) BURST32(finc, e, end, last, B0, B1, B2, B3);
    }
#pragma unroll
    for (int off = 8; off < 64; off <<= 1) {
        A0.x += __shfl_xor(A0.x, off);
        A0.y += __shfl_xor(A0.y, off);
        A1.x += __shfl_xor(A1.x, off);
        A1.y += __shfl_xor(A1.y, off);
        A2.x += __shfl_xor(A2.x, off);
        A2.y += __shfl_xor(A2.y, off);
        A3.x += __shfl_xor(A3.x, off);
        A3.y += __shfl_xor(A3.y, off);
        B0.x += __shfl_xor(B0.x, off);
        B0.y += __shfl_xor(B0.y, off);
        B1.x += __shfl_xor(B1.x, off);
        B1.y += __shfl_xor(B1.y, off);
        B2.x += __shfl_xor(B2.x, off);
        B2.y += __shfl_xor(B2.y, off);
        B3.x += __shfl_xor(B3.x, off);
        B3.y += __shfl_xor(B3.y, off);
    }
    // layers 0..2: fp32 table row + ebf1 row + ebf2 row (each lane: dims q*8..q*8+7)
    {
        const float4* fp = (const float4*)(uemb + (size_t)nu * DIM + q * 8);
        float4 fa = fp[0], fb = fp[1];
        uint4 u1 = *(const uint4*)(ebf1 + (size_t)nu * DIM + q * 8);
        uint4 u2 = *(const uint4*)(ebf2 + (size_t)nu * DIM + q * 8);
        A0.x += fa.x + blo(u1.x) + blo(u2.x); A0.y += fa.y + bhi(u1.x) + bhi(u2.x);
        A1.x += fa.z + blo(u1.y) + blo(u2.y); A1.y += fa.w + bhi(u1.y) + bhi(u2.y);
        A2.x += fb.x + blo(u1.z) + blo(u2.z); A2.y += fb.y + bhi(u1.z) + bhi(u2.z);
        A3.x += fb.z + blo(u1.w) + blo(u2.w); A3.y += fb.w + bhi(u1.w) + bhi(u2.w);
    }
    {
        const float4* fp = (const float4*)(iemb + (size_t)ii * DIM + q * 8);
        float4 fa = fp[0], fb = fp[1];
        uint4 u1 = *(const uint4*)(ebf1 + (size_t)ni * DIM + q * 8);
        uint4 u2 = *(const uint4*)(ebf2 + (size_t)ni * DIM + q * 8);
        B0.x += fa.x + blo(u1.x) + blo(u2.x); B0.y += fa.y + bhi(u1.x) + bhi(u2.x);
        B1.x += fa.z + blo(u1.y) + blo(u2.y); B1.y += fa.w + bhi(u1.y) + bhi(u2.y);
        B2.x += fb.x + blo(u1.z) + blo(u2.z); B2.y += fb.y + bhi(u1.z) + bhi(u2.z);
        B3.x += fb.z + blo(u1.w) + blo(u2.w); B3.y += fb.w + bhi(u1.w) + bhi(u2.w);
    }
    // dot: per-lane 8-dim product, reduce across q (lanes 0..7 cover all 64 dims)
    float p = A0.x * B0.x + A0.y * B0.y + A1.x * B1.x + A1.y * B1.y +
              A2.x * B2.x + A2.y * B2.y + A3.x * B3.x + A3.y * B3.y;
    p += __shfl_xor(p, 1);
    p += __shfl_xor(p, 2);
    p += __shfl_xor(p, 4);
    if (lane == 0) out[b] = p * (1.0f / 16.0f);  // (acc/4)·(acc/4)
}

// ---------------- launch ----------------

extern "C" void kernel_launch(void* const* d_in, const int* in_sizes, int n_in,
                              void* d_out, int out_size, void* d_ws, size_t ws_size,
                              hipStream_t stream) {
    const float* user_emb = (const float*)d_in[0];
    const float* item_emb = (const float*)d_in[1];
    const float* vals = (const float*)d_in[2];
    const int* src = (const int*)d_in[3];
    const int* dst = (const int*)d_in[4];
    const int* users = (const int*)d_in[5];
    const int* items = (const int*)d_in[6];
    float* out = (float*)d_out;

    char* ws = (char*)d_ws;
    size_t off = 0;
    auto alloc = [&](size_t bytes) {
        char* p = ws + off;
        off += (bytes + 255) & ~(size_t)255;
        return p;
    };
    ushort* ebf0 = (ushort*)alloc((size_t)N_NODES * DIM * 2);  // 19.2 MB bf16 concat tables
    ushort* ebf1 = (ushort*)alloc((size_t)N_NODES * DIM * 2);  // layer-1 out (aliases tmp lo)
    ushort* ebf2 = (ushort*)alloc((size_t)N_NODES * DIM * 2);  // layer-2 out (aliases tmp hi)
    int2* fin = (int2*)alloc((size_t)N_EDGES * 8);             // 32 MB dense CSR records
    int* row_ptr = (int*)alloc((size_t)(N_NODES + 1) * 4);
    int* gcur = (int*)alloc((size_t)NBKT * 4);
    // 37.75 MB fixed-stride partition scratch aliases ebf1+ebf2 (38.4 MB contiguous);
    // tmp is dead after k_bsort, before ebf1/2 are first written.
    int2* tmp = (int2*)ebf1;

    hipMemsetAsync(gcur, 0, (size_t)NBKT * 4, stream);

    // fused convert + partition (independent workloads overlap on the machine)
    k_cvtpart<<<PA_BLOCKS + CVT_BLOCKS, 256, 0, stream>>>(
        user_emb, item_emb, ebf0, src, dst, vals, gcur, tmp);
    k_bsort<<<NBKT, 512, (size_t)STRIDE * 8, stream>>>(tmp, gcur, row_ptr, fin);

    int spmm_blocks = (N_NODES * 64 + 255) / 256;  // one wave per node
    // layer 1: ebf0 -> ebf1; layer 2: ebf1 -> ebf2
    k_spmm16<<<spmm_blocks, 256, 0, stream>>>(ebf0, ebf1, row_ptr, fin);
    k_spmm16<<<spmm_blocks, 256, 0, stream>>>(ebf1, ebf2, row_ptr, fin);
    // fused sampled tail: layer-3 + layer-0/1/2 accumulate + dot
    k_sampdot<<<(BATCH * 64 + 255) / 256, 256, 0, stream>>>(
        user_emb, item_emb, ebf1, ebf2, row_ptr, fin, users, items, out);
}